// Round 1
// baseline (23295.280 us; speedup 1.0000x reference)
//
#include <hip/hip_runtime.h>
#include <math.h>

#define BB 48
#define TT 256
#define DD 1024

// C[m,n] = sum_k A[m,k]*Bm[n,k]  (both row-major along k), tiled 64x64x16.
// MODE 0: C = (acc + bias[n]) * scale   (projection)
// MODE 1: C = (m==n) ? 0 : exp(acc)     (scores -> A matrix)
template<int MODE>
__global__ void gemm_bt_kernel(const float* __restrict__ Ag, const float* __restrict__ Bg,
                               const float* __restrict__ bias, float* __restrict__ Cg,
                               int M, int N, int Kd, float scale,
                               long long sA, long long sB, long long sC) {
  const float* A  = Ag + (long long)blockIdx.z * sA;
  const float* Bm = Bg + (long long)blockIdx.z * sB;
  float*       C  = Cg + (long long)blockIdx.z * sC;
  __shared__ float As[16][65];   // +1 pad: avoids 16-way bank conflict on staging writes
  __shared__ float Bs[16][65];
  int tid = threadIdx.x;
  int tx = tid & 15, ty = tid >> 4;
  int m0 = blockIdx.x * 64, n0 = blockIdx.y * 64;
  float acc[4][4] = {};
  for (int k0 = 0; k0 < Kd; k0 += 16) {
    #pragma unroll
    for (int q = 0; q < 4; ++q) {
      int e = tid + q * 256;
      int r = e >> 4, kk = e & 15;
      As[kk][r] = A[(long long)(m0 + r) * Kd + k0 + kk];
      Bs[kk][r] = Bm[(long long)(n0 + r) * Kd + k0 + kk];
    }
    __syncthreads();
    #pragma unroll
    for (int kk = 0; kk < 16; ++kk) {
      float a4[4], b4[4];
      #pragma unroll
      for (int i = 0; i < 4; ++i) a4[i] = As[kk][ty * 4 + i];
      #pragma unroll
      for (int j = 0; j < 4; ++j) b4[j] = Bs[kk][tx * 4 + j];
      #pragma unroll
      for (int i = 0; i < 4; ++i)
        #pragma unroll
        for (int j = 0; j < 4; ++j)
          acc[i][j] = fmaf(a4[i], b4[j], acc[i][j]);
    }
    __syncthreads();
  }
  #pragma unroll
  for (int i = 0; i < 4; ++i) {
    int m = m0 + ty * 4 + i;
    #pragma unroll
    for (int j = 0; j < 4; ++j) {
      int n = n0 + tx * 4 + j;
      float v = acc[i][j];
      if (MODE == 0) {
        v = (v + bias[n]) * scale;
      } else {
        v = expf(v);
        if (m == n) v = 0.f;   // zero diagonal
      }
      C[(long long)m * N + n] = v;
    }
  }
}

// f[row] = dot(inp[row,:], Wr) + br ; one wave per row
__global__ void root_kernel(const float* __restrict__ inp, const float* __restrict__ Wr,
                            const float* __restrict__ br, float* __restrict__ f) {
  int wave = threadIdx.x >> 6, lane = threadIdx.x & 63;
  int row = blockIdx.x * 4 + wave;
  const float* r = inp + (long long)row * DD;
  float s = 0.f;
  #pragma unroll
  for (int q = 0; q < DD / 64; ++q) s += r[lane + q * 64] * Wr[lane + q * 64];
  #pragma unroll
  for (int off = 32; off; off >>= 1) s += __shfl_down(s, off);
  if (lane == 0) f[row] = s + br[0];
}

// colsum[b,j] = sum_i A[b,i,j]  (coalesced: lane j walks rows)
__global__ void colsum_kernel(const float* __restrict__ Aall, float* __restrict__ cs) {
  int b = blockIdx.x, j = threadIdx.x;
  const float* Ab = Aall + (long long)b * TT * TT;
  float s = 0.f;
  for (int i = 0; i < TT; ++i) s += Ab[i * TT + j];
  cs[b * TT + j] = s;
}

// L[b,i,j] = (i==0) ? f[b,j] : -A[b,i,j] + (i==j)*colsum[b,j]
__global__ void buildL_kernel(const float* __restrict__ Aall, const float* __restrict__ cs,
                              const float* __restrict__ f, float* __restrict__ L) {
  int bi = blockIdx.x;           // b*256 + i
  int b = bi >> 8, i = bi & 255, j = threadIdx.x;
  float v;
  if (i == 0) v = f[b * TT + j];
  else {
    v = -Aall[(long long)bi * TT + j];
    if (i == j) v += cs[b * TT + j];
  }
  L[(long long)bi * TT + j] = v;
}

// In-place Gauss-Jordan inverse (principal pivot transform), one block per batch.
// Pivot order 1..255 then 0: rows 1..255 are diagonally dominant (diag=colsum~300),
// row 0 (small root scores) pivoted last -> numerically stable without row swaps.
__global__ void __launch_bounds__(1024) gj_kernel(float* __restrict__ Lall) {
  float* M = Lall + (long long)blockIdx.x * TT * TT;
  __shared__ float rowk[TT], colk[TT];
  int tid = threadIdx.x;
  int i = tid >> 2;              // row owned (4 threads per row)
  int jb = (tid & 3) * 64;       // 64-column chunk
  for (int step = 0; step < TT; ++step) {
    int k = (step + 1) & 255;    // 1,2,...,255,0
    if (tid < 256) rowk[tid] = M[k * TT + tid];
    else if (tid < 512) colk[tid - 256] = M[(tid - 256) * TT + k];
    __syncthreads();
    float ip = 1.0f / rowk[k];
    if (i == k) {
      for (int jj = 0; jj < 64; ++jj) {
        int j = jb + jj;
        M[i * TT + j] = (j == k) ? ip : rowk[j] * ip;
      }
    } else {
      float cip = colk[i] * ip;
      for (int jj = 0; jj < 64; ++jj) {
        int j = jb + jj;
        float v = (j == k) ? (-cip) : (M[i * TT + j] - cip * rowk[j]);
        M[i * TT + j] = v;
      }
    }
    __syncthreads();
  }
}

// df[b,j,0]   = f[b,j]*Linv[b,j,0]
// df[b,j,i+1] = A[b,i,j] * ((j>0)*Linv[b,j,j] - (i>0)*Linv[b,j,i])
__global__ void out_kernel(const float* __restrict__ Aall, const float* __restrict__ Linv,
                           const float* __restrict__ f, float* __restrict__ out) {
  int bj = blockIdx.x;           // b*256 + j
  int b = bj >> 8, j = bj & 255;
  const float* Lrow = Linv + (long long)b * TT * TT + j * TT;
  const float* Ab   = Aall + (long long)b * TT * TT;
  float fbj = f[bj];
  float dg = Lrow[j];
  float l0 = Lrow[0];
  float* orow = out + (long long)bj * (TT + 1);
  for (int c = threadIdx.x; c < TT + 1; c += 256) {
    float v;
    if (c == 0) v = fbj * l0;
    else {
      int i = c - 1;
      float aij = Ab[i * TT + j];
      float t1 = (j > 0) ? dg : 0.f;
      float t2 = (i > 0) ? Lrow[i] : 0.f;
      v = aij * (t1 - t2);
    }
    orow[c] = v;
  }
}

extern "C" void kernel_launch(void* const* d_in, const int* in_sizes, int n_in,
                              void* d_out, int out_size, void* d_ws, size_t ws_size,
                              hipStream_t stream) {
  const float* inp = (const float*)d_in[0];
  const float* Wk  = (const float*)d_in[1];
  const float* bk  = (const float*)d_in[2];
  const float* Wq  = (const float*)d_in[3];
  const float* bq  = (const float*)d_in[4];
  const float* Wr  = (const float*)d_in[5];
  const float* br  = (const float*)d_in[6];
  float* out = (float*)d_out;

  float* ws = (float*)d_ws;
  float* K  = ws;                       // 12,582,912 f32
  float* Q  = K + (long long)BB * TT * DD;
  float* f  = Q + (long long)BB * TT * DD;   // 12,288
  float* cs = f + BB * TT;                   // 12,288
  float* A  = cs + BB * TT;                  // 3,145,728
  float* L  = A + (long long)BB * TT * TT;   // 3,145,728

  const int M = BB * TT;  // 12288

  // key = inp @ Wk^T + bk ; query = (inp @ Wq^T + bq)/32
  dim3 g1(M / 64, DD / 64, 1);
  gemm_bt_kernel<0><<<g1, 256, 0, stream>>>(inp, Wk, bk, K, M, DD, DD, 1.0f, 0, 0, 0);
  gemm_bt_kernel<0><<<g1, 256, 0, stream>>>(inp, Wq, bq, Q, M, DD, DD, 0.03125f, 0, 0, 0);

  // f_i = inp @ Wr^T + br
  root_kernel<<<M / 4, 256, 0, stream>>>(inp, Wr, br, f);

  // A[b,t,s] = (t==s)?0:exp(Q[b,t,:].K[b,s,:])
  dim3 g2(TT / 64, TT / 64, BB);
  gemm_bt_kernel<1><<<g2, 256, 0, stream>>>(Q, K, nullptr, A, TT, TT, DD, 1.0f,
                                            (long long)TT * DD, (long long)TT * DD,
                                            (long long)TT * TT);

  colsum_kernel<<<BB, TT, 0, stream>>>(A, cs);
  buildL_kernel<<<BB * TT, TT, 0, stream>>>(A, cs, f, L);

  // L <- inv(L)
  gj_kernel<<<BB, 1024, 0, stream>>>(L);

  out_kernel<<<BB * TT, TT, 0, stream>>>(A, L, f, out);
}

// Round 2
// 1998.631 us; speedup vs baseline: 11.6556x; 11.6556x over previous
//
#include <hip/hip_runtime.h>
#include <math.h>

#define BB 48
#define TT 256
#define DD 1024

// C[m,n] = sum_k A[m,k]*Bm[n,k]  (both row-major along k), tiled 64x64x16.
// MODE 0: C = (acc + bias[n]) * scale   (projection)
// MODE 1: C = (m==n) ? 0 : exp(acc)     (scores -> A matrix)
template<int MODE>
__global__ void gemm_bt_kernel(const float* __restrict__ Ag, const float* __restrict__ Bg,
                               const float* __restrict__ bias, float* __restrict__ Cg,
                               int M, int N, int Kd, float scale,
                               long long sA, long long sB, long long sC) {
  const float* A  = Ag + (long long)blockIdx.z * sA;
  const float* Bm = Bg + (long long)blockIdx.z * sB;
  float*       C  = Cg + (long long)blockIdx.z * sC;
  __shared__ float As[16][65];   // +1 pad: avoids 16-way bank conflict on staging writes
  __shared__ float Bs[16][65];
  int tid = threadIdx.x;
  int tx = tid & 15, ty = tid >> 4;
  int m0 = blockIdx.x * 64, n0 = blockIdx.y * 64;
  float acc[4][4] = {};
  for (int k0 = 0; k0 < Kd; k0 += 16) {
    #pragma unroll
    for (int q = 0; q < 4; ++q) {
      int e = tid + q * 256;
      int r = e >> 4, kk = e & 15;
      As[kk][r] = A[(long long)(m0 + r) * Kd + k0 + kk];
      Bs[kk][r] = Bm[(long long)(n0 + r) * Kd + k0 + kk];
    }
    __syncthreads();
    #pragma unroll
    for (int kk = 0; kk < 16; ++kk) {
      float a4[4], b4[4];
      #pragma unroll
      for (int i = 0; i < 4; ++i) a4[i] = As[kk][ty * 4 + i];
      #pragma unroll
      for (int j = 0; j < 4; ++j) b4[j] = Bs[kk][tx * 4 + j];
      #pragma unroll
      for (int i = 0; i < 4; ++i)
        #pragma unroll
        for (int j = 0; j < 4; ++j)
          acc[i][j] = fmaf(a4[i], b4[j], acc[i][j]);
    }
    __syncthreads();
  }
  #pragma unroll
  for (int i = 0; i < 4; ++i) {
    int m = m0 + ty * 4 + i;
    #pragma unroll
    for (int j = 0; j < 4; ++j) {
      int n = n0 + tx * 4 + j;
      float v = acc[i][j];
      if (MODE == 0) {
        v = (v + bias[n]) * scale;
      } else {
        v = expf(v);
        if (m == n) v = 0.f;   // zero diagonal
      }
      C[(long long)m * N + n] = v;
    }
  }
}

// f[row] = dot(inp[row,:], Wr) + br ; one wave per row
__global__ void root_kernel(const float* __restrict__ inp, const float* __restrict__ Wr,
                            const float* __restrict__ br, float* __restrict__ f) {
  int wave = threadIdx.x >> 6, lane = threadIdx.x & 63;
  int row = blockIdx.x * 4 + wave;
  const float* r = inp + (long long)row * DD;
  float s = 0.f;
  #pragma unroll
  for (int q = 0; q < DD / 64; ++q) s += r[lane + q * 64] * Wr[lane + q * 64];
  #pragma unroll
  for (int off = 32; off; off >>= 1) s += __shfl_down(s, off);
  if (lane == 0) f[row] = s + br[0];
}

// colsum[b,j] = sum_i A[b,i,j]  (coalesced: lane j walks rows)
__global__ void colsum_kernel(const float* __restrict__ Aall, float* __restrict__ cs) {
  int b = blockIdx.x, j = threadIdx.x;
  const float* Ab = Aall + (long long)b * TT * TT;
  float s = 0.f;
  for (int i = 0; i < TT; ++i) s += Ab[i * TT + j];
  cs[b * TT + j] = s;
}

// L[b,i,j] = (i==0) ? f[b,j] : -A[b,i,j] + (i==j)*colsum[b,j]
__global__ void buildL_kernel(const float* __restrict__ Aall, const float* __restrict__ cs,
                              const float* __restrict__ f, float* __restrict__ L) {
  int bi = blockIdx.x;           // b*256 + i
  int b = bi >> 8, i = bi & 255, j = threadIdx.x;
  float v;
  if (i == 0) v = f[b * TT + j];
  else {
    v = -Aall[(long long)bi * TT + j];
    if (i == j) v += cs[b * TT + j];
  }
  L[(long long)bi * TT + j] = v;
}

// Register-resident in-place Gauss-Jordan inverse, one 1024-thread block per batch.
// The whole 256x256 matrix lives in the block's VGPRs: thread tid owns row
// i=tid>>2, contiguous column chunk c=tid&3 (64 floats = 64 VGPRs). Per pivot
// step only the pivot row (256 f32) and pivot column (256 f32) go through LDS;
// the NEXT pivot's row/col are extracted during the update loop (jj is a
// compile-time literal vs uniform scalar -> no runtime register indexing).
// Global traffic: one 256 KB load + one 256 KB store per matrix, total.
// Pivot order 1..255 then 0 (rows 1..255 diagonally dominant; root row last).
__global__ void __launch_bounds__(1024, 4) gj_kernel(float* __restrict__ Lall) {
  float* Mb = Lall + (long long)blockIdx.x * TT * TT;
  // rowk chunks padded to 68 floats: chunk bases c*68 land on banks {0,4,8,12}
  // -> the four broadcast groups of a wave hit disjoint banks (conflict-free).
  __shared__ __align__(16) float rowk[4 * 68];
  __shared__ float colk[TT];
  const int tid = threadIdx.x;
  const int i  = tid >> 2;        // owned row
  const int c  = tid & 3;         // column chunk
  const int jb = c * 64;          // first owned column

  float r[64];
  { // load my 64 elements (16x float4)
    const float4* src = (const float4*)(Mb + (long long)i * TT + jb);
    #pragma unroll
    for (int q = 0; q < 16; ++q) {
      float4 v = src[q];
      r[4*q+0] = v.x; r[4*q+1] = v.y; r[4*q+2] = v.z; r[4*q+3] = v.w;
    }
  }

  // bootstrap: first pivot is k=1 -> publish row 1 and col 1 (chunk 0, offset 1)
  if (i == 1) {
    float4* w = (float4*)(rowk + c * 68);
    #pragma unroll
    for (int q = 0; q < 16; ++q) w[q] = make_float4(r[4*q], r[4*q+1], r[4*q+2], r[4*q+3]);
  }
  if (c == 0) colk[i] = r[1];
  __syncthreads();

  for (int step = 0; step < TT; ++step) {
    const int k      = (step + 1) & 255;   // pivot order 1..255, 0
    const bool last  = (step == TT - 1);
    const int k_next = (step + 2) & 255;
    const int ck_n   = k_next >> 6;        // chunk holding next pivot column
    const int ko_n   = k_next & 63;        // offset within that chunk (uniform)

    const float piv = rowk[(k >> 6) * 68 + (k & 63)];  // broadcast read
    const float ip  = 1.0f / piv;
    const int   kl  = k - jb;              // local index of column k (may be out of [0,64))
    float colv = 0.f;

    const float4* rk4 = (const float4*)(rowk + c * 68);
    if (i == k) {
      // pivot row: M'[k][j] = M[k][j]/p ; M'[k][k] = 1/p
      #pragma unroll
      for (int q = 0; q < 16; ++q) {
        float4 rv = rk4[q];
        float rr[4] = {rv.x, rv.y, rv.z, rv.w};
        #pragma unroll
        for (int l = 0; l < 4; ++l) {
          const int jj = 4*q + l;
          float v = rr[l] * ip;
          if (jj == kl) v = ip;
          r[jj] = v;
          if (jj == ko_n) colv = v;
        }
      }
    } else {
      // other rows: M'[i][j] = M[i][j] - (M[i][k]/p)*M[k][j] ; M'[i][k] = -M[i][k]/p
      const float cip = colk[i] * ip;
      #pragma unroll
      for (int q = 0; q < 16; ++q) {
        float4 rv = rk4[q];
        float rr[4] = {rv.x, rv.y, rv.z, rv.w};
        #pragma unroll
        for (int l = 0; l < 4; ++l) {
          const int jj = 4*q + l;
          float v = fmaf(-cip, rr[l], r[jj]);
          if (jj == kl) v = -cip;
          r[jj] = v;
          if (jj == ko_n) colv = v;
        }
      }
    }

    __syncthreads();   // all reads of rowk/colk done before overwrite
    if (!last) {
      if (i == k_next) {
        float4* w = (float4*)(rowk + c * 68);
        #pragma unroll
        for (int q = 0; q < 16; ++q) w[q] = make_float4(r[4*q], r[4*q+1], r[4*q+2], r[4*q+3]);
      }
      if (c == ck_n) colk[i] = colv;
    }
    __syncthreads();
  }

  { // store back (in place)
    float4* dst = (float4*)(Mb + (long long)i * TT + jb);
    #pragma unroll
    for (int q = 0; q < 16; ++q)
      dst[q] = make_float4(r[4*q], r[4*q+1], r[4*q+2], r[4*q+3]);
  }
}

// df[b,j,0]   = f[b,j]*Linv[b,j,0]
// df[b,j,i+1] = A[b,i,j] * ((j>0)*Linv[b,j,j] - (i>0)*Linv[b,j,i])
__global__ void out_kernel(const float* __restrict__ Aall, const float* __restrict__ Linv,
                           const float* __restrict__ f, float* __restrict__ out) {
  int bj = blockIdx.x;           // b*256 + j
  int b = bj >> 8, j = bj & 255;
  const float* Lrow = Linv + (long long)b * TT * TT + j * TT;
  const float* Ab   = Aall + (long long)b * TT * TT;
  float fbj = f[bj];
  float dg = Lrow[j];
  float l0 = Lrow[0];
  float* orow = out + (long long)bj * (TT + 1);
  for (int c = threadIdx.x; c < TT + 1; c += 256) {
    float v;
    if (c == 0) v = fbj * l0;
    else {
      int i = c - 1;
      float aij = Ab[i * TT + j];
      float t1 = (j > 0) ? dg : 0.f;
      float t2 = (i > 0) ? Lrow[i] : 0.f;
      v = aij * (t1 - t2);
    }
    orow[c] = v;
  }
}

extern "C" void kernel_launch(void* const* d_in, const int* in_sizes, int n_in,
                              void* d_out, int out_size, void* d_ws, size_t ws_size,
                              hipStream_t stream) {
  const float* inp = (const float*)d_in[0];
  const float* Wk  = (const float*)d_in[1];
  const float* bk  = (const float*)d_in[2];
  const float* Wq  = (const float*)d_in[3];
  const float* bq  = (const float*)d_in[4];
  const float* Wr  = (const float*)d_in[5];
  const float* br  = (const float*)d_in[6];
  float* out = (float*)d_out;

  float* ws = (float*)d_ws;
  float* K  = ws;                       // 12,582,912 f32
  float* Q  = K + (long long)BB * TT * DD;
  float* f  = Q + (long long)BB * TT * DD;   // 12,288
  float* cs = f + BB * TT;                   // 12,288
  float* A  = cs + BB * TT;                  // 3,145,728
  float* L  = A + (long long)BB * TT * TT;   // 3,145,728

  const int M = BB * TT;  // 12288

  // key = inp @ Wk^T + bk ; query = (inp @ Wq^T + bq)/32
  dim3 g1(M / 64, DD / 64, 1);
  gemm_bt_kernel<0><<<g1, 256, 0, stream>>>(inp, Wk, bk, K, M, DD, DD, 1.0f, 0, 0, 0);
  gemm_bt_kernel<0><<<g1, 256, 0, stream>>>(inp, Wq, bq, Q, M, DD, DD, 0.03125f, 0, 0, 0);

  // f_i = inp @ Wr^T + br
  root_kernel<<<M / 4, 256, 0, stream>>>(inp, Wr, br, f);

  // A[b,t,s] = (t==s)?0:exp(Q[b,t,:].K[b,s,:])
  dim3 g2(TT / 64, TT / 64, BB);
  gemm_bt_kernel<1><<<g2, 256, 0, stream>>>(Q, K, nullptr, A, TT, TT, DD, 1.0f,
                                            (long long)TT * DD, (long long)TT * DD,
                                            (long long)TT * TT);

  colsum_kernel<<<BB, TT, 0, stream>>>(A, cs);
  buildL_kernel<<<BB * TT, TT, 0, stream>>>(A, cs, f, L);

  // L <- inv(L)
  gj_kernel<<<BB, 1024, 0, stream>>>(L);

  out_kernel<<<BB * TT, TT, 0, stream>>>(A, L, f, out);
}

// Round 3
// 1130.311 us; speedup vs baseline: 20.6096x; 1.7682x over previous
//
#include <hip/hip_runtime.h>
#include <hip/hip_bf16.h>
#include <math.h>

#define BB 48
#define TT 256
#define DD 1024
#define BK 32

typedef __attribute__((ext_vector_type(8))) short bf16x8;
typedef __attribute__((ext_vector_type(8))) unsigned short ushortx8;
typedef __attribute__((ext_vector_type(4))) float f32x4;

__device__ __forceinline__ unsigned short bfb(float x) {
  __hip_bfloat16 h = __float2bfloat16(x);   // RNE
  return __builtin_bit_cast(unsigned short, h);
}
__device__ __forceinline__ float fromb(unsigned short u) {
  unsigned v = (unsigned)u << 16;
  return __builtin_bit_cast(float, v);
}
__device__ __forceinline__ void gl16(const void* g, void* l) {
  __builtin_amdgcn_global_load_lds((const __attribute__((address_space(1))) unsigned int*)g,
                                   (__attribute__((address_space(3))) unsigned int*)l, 16, 0, 0);
}

// split x -> hi bf16 + lo bf16 (for Wk, Wq; n multiple of 1024)
__global__ void split_kernel(const float* __restrict__ src, unsigned short* __restrict__ hi,
                             unsigned short* __restrict__ lo, int n) {
  int idx = blockIdx.x * blockDim.x + threadIdx.x;
  if (idx * 4 >= n) return;
  float4 v = ((const float4*)src)[idx];
  ushort4 h, l;
  h.x = bfb(v.x); l.x = bfb(v.x - fromb(h.x));
  h.y = bfb(v.y); l.y = bfb(v.y - fromb(h.y));
  h.z = bfb(v.z); l.z = bfb(v.z - fromb(h.z));
  h.w = bfb(v.w); l.w = bfb(v.w - fromb(h.w));
  ((ushort4*)hi)[idx] = h;
  ((ushort4*)lo)[idx] = l;
}

// Split-bf16 MFMA GEMM: C[m,n] = sum_k A[m,k]*B[n,k], computed as
// Ahi.Bhi + Ahi.Blo + Alo.Bhi  (3x mfma_f32_16x16x32_bf16) ~ fp32 accurate.
// 128x128 tile, BK=32, 4 waves (each wave owns a 64x64 quadrant, 4x4 16x16 frags).
// MODE 0 (projection): A = fp32 streamed (in-kernel hi/lo split), B = pre-split
//   bf16 via global_load_lds (double-buffered, issued under the MFMA block).
//   Epilogue: C = (acc + bias[n]) * scale, fp32.
// MODE 1 (einsum): both A and B fp32 streamed + in-kernel split.
//   Epilogue: C = (m==n) ? 0 : exp(acc), fp32.
template<int MODE>
__global__ __launch_bounds__(256) void mfma_gemm(
    const float* __restrict__ Af, const float* __restrict__ Bf,
    const unsigned short* __restrict__ Bhi_g, const unsigned short* __restrict__ Blo_g,
    const float* __restrict__ bias, float scale, float* __restrict__ Cg,
    int Nsz, long long sA, long long sB, long long sC) {
  __shared__ char lds[49152];
  char* sAhi = lds;                 // [128][32] bf16 = 8 KB
  char* sAlo = lds + 8192;
  char* sBhi = lds + 16384;         // MODE0: 2 x 8 KB dbuf ; MODE1: 8 KB
  char* sBlo = (MODE == 0) ? lds + 32768 : lds + 24576;

  const int tid = threadIdx.x;
  const int m0 = blockIdx.x * 128, n0 = blockIdx.y * 128;
  const float* Ab = Af + (long long)blockIdx.z * sA;
  float*       Cb = Cg + (long long)blockIdx.z * sC;

  // streamed-operand staging: thread covers row sr, 16 elems starting at col sh
  const int sr = tid >> 1, sh = (tid & 1) * 16;
  const float* aG = Ab + (long long)(m0 + sr) * DD + sh;

  float4 av[4], bv[4];
  const float* bG = nullptr;
  const unsigned short* bg0 = nullptr;
  const unsigned short* bl0 = nullptr;
  if (MODE == 0) {
    bg0 = Bhi_g + (long long)(n0 + (tid >> 2)) * DD + (tid & 3) * 8;
    bl0 = Blo_g + (long long)(n0 + (tid >> 2)) * DD + (tid & 3) * 8;
  } else {
    const float* Bb = Bf + (long long)blockIdx.z * sB;
    bG = Bb + (long long)(n0 + sr) * DD + sh;
  }

  const int lane = tid & 63, wid = tid >> 6;
  const int wr = wid >> 1, wc = wid & 1;
  const int fr = lane & 15, fq = lane >> 4;

  f32x4 acc[4][4] = {};

  // ---- prologue: step 0 loads in flight
  {
    const float4* p = (const float4*)(aG);
    av[0] = p[0]; av[1] = p[1]; av[2] = p[2]; av[3] = p[3];
    if (MODE == 0) {
      gl16(bg0,            sBhi + tid * 16);
      gl16(bg0 + 64 * DD,  sBhi + tid * 16 + 4096);
      gl16(bl0,            sBlo + tid * 16);
      gl16(bl0 + 64 * DD,  sBlo + tid * 16 + 4096);
    } else {
      const float4* q = (const float4*)(bG);
      bv[0] = q[0]; bv[1] = q[1]; bv[2] = q[2]; bv[3] = q[3];
    }
  }

  const int NS = DD / BK;   // 32
  for (int s = 0; s < NS; ++s) {
    const int bb = (MODE == 0) ? ((s & 1) << 13) : 0;

    // convert current streamed tiles (register-only work, before barrier)
    ushortx8 ah0, ah1, al0, al1, bh0, bh1, blo0, blo1;
    {
      const float* af = (const float*)av;
      #pragma unroll
      for (int e = 0; e < 8; ++e) {
        unsigned short h = bfb(af[e]);      ah0[e] = h; al0[e] = bfb(af[e] - fromb(h));
        unsigned short h2 = bfb(af[e + 8]); ah1[e] = h2; al1[e] = bfb(af[e + 8] - fromb(h2));
      }
      if (MODE == 1) {
        const float* bf = (const float*)bv;
        #pragma unroll
        for (int e = 0; e < 8; ++e) {
          unsigned short h = bfb(bf[e]);      bh0[e] = h; blo0[e] = bfb(bf[e] - fromb(h));
          unsigned short h2 = bfb(bf[e + 8]); bh1[e] = h2; blo1[e] = bfb(bf[e + 8] - fromb(h2));
        }
      }
    }

    __syncthreads();   // prev-step LDS reads done; vmcnt drained (B gloads / A regs landed)

    { // publish streamed tiles to LDS
      *(ushortx8*)(sAhi + sr * 64 + sh * 2)      = ah0;
      *(ushortx8*)(sAhi + sr * 64 + sh * 2 + 16) = ah1;
      *(ushortx8*)(sAlo + sr * 64 + sh * 2)      = al0;
      *(ushortx8*)(sAlo + sr * 64 + sh * 2 + 16) = al1;
      if (MODE == 1) {
        *(ushortx8*)(sBhi + sr * 64 + sh * 2)      = bh0;
        *(ushortx8*)(sBhi + sr * 64 + sh * 2 + 16) = bh1;
        *(ushortx8*)(sBlo + sr * 64 + sh * 2)      = blo0;
        *(ushortx8*)(sBlo + sr * 64 + sh * 2 + 16) = blo1;
      }
    }

    __syncthreads();   // tiles visible

    // issue next-step loads NOW so they fly under the MFMA block
    if (s + 1 < NS) {
      const float4* p = (const float4*)(aG + (s + 1) * BK);
      av[0] = p[0]; av[1] = p[1]; av[2] = p[2]; av[3] = p[3];
      if (MODE == 0) {
        const int nb = ((s + 1) & 1) << 13;
        gl16(bg0 + (s + 1) * BK,            sBhi + nb + tid * 16);
        gl16(bg0 + (s + 1) * BK + 64 * DD,  sBhi + nb + tid * 16 + 4096);
        gl16(bl0 + (s + 1) * BK,            sBlo + nb + tid * 16);
        gl16(bl0 + (s + 1) * BK + 64 * DD,  sBlo + nb + tid * 16 + 4096);
      } else {
        const float4* q = (const float4*)(bG + (s + 1) * BK);
        bv[0] = q[0]; bv[1] = q[1]; bv[2] = q[2]; bv[3] = q[3];
      }
    }

    // fragments + 48 MFMA
    bf16x8 fah[4], fal[4], fbh[4], fbl[4];
    #pragma unroll
    for (int im = 0; im < 4; ++im) {
      const int off = (wr * 64 + im * 16 + fr) * 64 + fq * 16;
      fah[im] = *(const bf16x8*)(sAhi + off);
      fal[im] = *(const bf16x8*)(sAlo + off);
    }
    #pragma unroll
    for (int jn = 0; jn < 4; ++jn) {
      const int off = (wc * 64 + jn * 16 + fr) * 64 + fq * 16;
      fbh[jn] = *(const bf16x8*)(sBhi + bb + off);
      fbl[jn] = *(const bf16x8*)(sBlo + bb + off);
    }
    #pragma unroll
    for (int im = 0; im < 4; ++im)
      #pragma unroll
      for (int jn = 0; jn < 4; ++jn) {
        acc[im][jn] = __builtin_amdgcn_mfma_f32_16x16x32_bf16(fah[im], fbh[jn], acc[im][jn], 0, 0, 0);
        acc[im][jn] = __builtin_amdgcn_mfma_f32_16x16x32_bf16(fah[im], fbl[jn], acc[im][jn], 0, 0, 0);
        acc[im][jn] = __builtin_amdgcn_mfma_f32_16x16x32_bf16(fal[im], fbh[jn], acc[im][jn], 0, 0, 0);
      }
  }

  // epilogue: C/D layout col=lane&15, row=(lane>>4)*4+reg  [verified m89/m91]
  #pragma unroll
  for (int im = 0; im < 4; ++im) {
    #pragma unroll
    for (int jn = 0; jn < 4; ++jn) {
      const int mbase = m0 + wr * 64 + im * 16 + fq * 4;
      const int n     = n0 + wc * 64 + jn * 16 + fr;
      #pragma unroll
      for (int reg = 0; reg < 4; ++reg) {
        const int m = mbase + reg;
        float v = acc[im][jn][reg];
        if (MODE == 0) {
          v = (v + bias[n]) * scale;
        } else {
          v = expf(v);
          if (m == n) v = 0.f;
        }
        Cb[(long long)m * Nsz + n] = v;
      }
    }
  }
}

// f[row] = dot(inp[row,:], Wr) + br ; one wave per row
__global__ void root_kernel(const float* __restrict__ inp, const float* __restrict__ Wr,
                            const float* __restrict__ br, float* __restrict__ f) {
  int wave = threadIdx.x >> 6, lane = threadIdx.x & 63;
  int row = blockIdx.x * 4 + wave;
  const float* r = inp + (long long)row * DD;
  float s = 0.f;
  #pragma unroll
  for (int q = 0; q < DD / 64; ++q) s += r[lane + q * 64] * Wr[lane + q * 64];
  #pragma unroll
  for (int off = 32; off; off >>= 1) s += __shfl_down(s, off);
  if (lane == 0) f[row] = s + br[0];
}

__global__ void colsum_kernel(const float* __restrict__ Aall, float* __restrict__ cs) {
  int b = blockIdx.x, j = threadIdx.x;
  const float* Ab = Aall + (long long)b * TT * TT;
  float s = 0.f;
  for (int i = 0; i < TT; ++i) s += Ab[i * TT + j];
  cs[b * TT + j] = s;
}

__global__ void buildL_kernel(const float* __restrict__ Aall, const float* __restrict__ cs,
                              const float* __restrict__ f, float* __restrict__ L) {
  int bi = blockIdx.x;           // b*256 + i
  int b = bi >> 8, i = bi & 255, j = threadIdx.x;
  float v;
  if (i == 0) v = f[b * TT + j];
  else {
    v = -Aall[(long long)bi * TT + j];
    if (i == j) v += cs[b * TT + j];
  }
  L[(long long)bi * TT + j] = v;
}

// Register-resident in-place Gauss-Jordan inverse, one 1024-thread block per batch.
// waves_per_eu(4,4): only 4 waves/EU possible for a 1024-thread block anyway ->
// give the allocator the full 128-VGPR budget so r[64] stays in arch VGPRs
// (round-2 counters showed VGPR_Count=64 -> half the array was in AGPRs).
__global__ __attribute__((amdgpu_flat_work_group_size(1024, 1024), amdgpu_waves_per_eu(4, 4)))
void gj_kernel(float* __restrict__ Lall) {
  float* Mb = Lall + (long long)blockIdx.x * TT * TT;
  __shared__ __align__(16) float rowk[4 * 68];
  __shared__ float colk[TT];
  const int tid = threadIdx.x;
  const int i  = tid >> 2;
  const int c  = tid & 3;
  const int jb = c * 64;

  float r[64];
  {
    const float4* src = (const float4*)(Mb + (long long)i * TT + jb);
    #pragma unroll
    for (int q = 0; q < 16; ++q) {
      float4 v = src[q];
      r[4*q+0] = v.x; r[4*q+1] = v.y; r[4*q+2] = v.z; r[4*q+3] = v.w;
    }
  }

  if (i == 1) {
    float4* w = (float4*)(rowk + c * 68);
    #pragma unroll
    for (int q = 0; q < 16; ++q) w[q] = make_float4(r[4*q], r[4*q+1], r[4*q+2], r[4*q+3]);
  }
  if (c == 0) colk[i] = r[1];
  __syncthreads();

  for (int step = 0; step < TT; ++step) {
    const int k      = (step + 1) & 255;
    const bool last  = (step == TT - 1);
    const int k_next = (step + 2) & 255;
    const int ck_n   = k_next >> 6;
    const int ko_n   = k_next & 63;

    const float piv = rowk[(k >> 6) * 68 + (k & 63)];
    const float ip  = 1.0f / piv;
    const int   kl  = k - jb;
    float colv = 0.f;

    const float4* rk4 = (const float4*)(rowk + c * 68);
    if (i == k) {
      #pragma unroll
      for (int q = 0; q < 16; ++q) {
        float4 rv = rk4[q];
        float rr[4] = {rv.x, rv.y, rv.z, rv.w};
        #pragma unroll
        for (int l = 0; l < 4; ++l) {
          const int jj = 4*q + l;
          float v = rr[l] * ip;
          if (jj == kl) v = ip;
          r[jj] = v;
          if (jj == ko_n) colv = v;
        }
      }
    } else {
      const float cip = colk[i] * ip;
      #pragma unroll
      for (int q = 0; q < 16; ++q) {
        float4 rv = rk4[q];
        float rr[4] = {rv.x, rv.y, rv.z, rv.w};
        #pragma unroll
        for (int l = 0; l < 4; ++l) {
          const int jj = 4*q + l;
          float v = fmaf(-cip, rr[l], r[jj]);
          if (jj == kl) v = -cip;
          r[jj] = v;
          if (jj == ko_n) colv = v;
        }
      }
    }

    __syncthreads();
    if (!last) {
      if (i == k_next) {
        float4* w = (float4*)(rowk + c * 68);
        #pragma unroll
        for (int q = 0; q < 16; ++q) w[q] = make_float4(r[4*q], r[4*q+1], r[4*q+2], r[4*q+3]);
      }
      if (c == ck_n) colk[i] = colv;
    }
    __syncthreads();
  }

  {
    float4* dst = (float4*)(Mb + (long long)i * TT + jb);
    #pragma unroll
    for (int q = 0; q < 16; ++q)
      dst[q] = make_float4(r[4*q], r[4*q+1], r[4*q+2], r[4*q+3]);
  }
}

__global__ void out_kernel(const float* __restrict__ Aall, const float* __restrict__ Linv,
                           const float* __restrict__ f, float* __restrict__ out) {
  int bj = blockIdx.x;           // b*256 + j
  int b = bj >> 8, j = bj & 255;
  const float* Lrow = Linv + (long long)b * TT * TT + j * TT;
  const float* Ab   = Aall + (long long)b * TT * TT;
  float fbj = f[bj];
  float dg = Lrow[j];
  float l0 = Lrow[0];
  float* orow = out + (long long)bj * (TT + 1);
  for (int c = threadIdx.x; c < TT + 1; c += 256) {
    float v;
    if (c == 0) v = fbj * l0;
    else {
      int i = c - 1;
      float aij = Ab[i * TT + j];
      float t1 = (j > 0) ? dg : 0.f;
      float t2 = (i > 0) ? Lrow[i] : 0.f;
      v = aij * (t1 - t2);
    }
    orow[c] = v;
  }
}

extern "C" void kernel_launch(void* const* d_in, const int* in_sizes, int n_in,
                              void* d_out, int out_size, void* d_ws, size_t ws_size,
                              hipStream_t stream) {
  const float* inp = (const float*)d_in[0];
  const float* Wk  = (const float*)d_in[1];
  const float* bk  = (const float*)d_in[2];
  const float* Wq  = (const float*)d_in[3];
  const float* bq  = (const float*)d_in[4];
  const float* Wr  = (const float*)d_in[5];
  const float* br  = (const float*)d_in[6];
  float* out = (float*)d_out;

  // workspace layout (floats); peak 121.7 MB (< 126.25 MB proven in round 1)
  float* ws = (float*)d_ws;
  const long long NI = (long long)BB * TT * DD;   // 12,582,912
  float* Qf = ws;                                 // [12288,1024] fp32
  float* Kf = Qf + NI;
  float* A  = Kf + NI;                            // 3,145,728
  float* f  = A + (long long)BB * TT * TT;        // 12,288
  float* cs = f + BB * TT;                        // 12,288
  unsigned short* WkHi = (unsigned short*)(cs + BB * TT);
  unsigned short* WkLo = WkHi + (long long)DD * DD;
  unsigned short* WqHi = WkLo + (long long)DD * DD;
  unsigned short* WqLo = WqHi + (long long)DD * DD;
  float* L = ws;                                  // aliases Qf (dead after einsum)

  const int M = BB * TT;  // 12288

  // pre-split weights to bf16 hi/lo
  split_kernel<<<DD * DD / 4 / 256, 256, 0, stream>>>(Wk, WkHi, WkLo, DD * DD);
  split_kernel<<<DD * DD / 4 / 256, 256, 0, stream>>>(Wq, WqHi, WqLo, DD * DD);

  // projections: key = inp @ Wk^T + bk ; query = (inp @ Wq^T + bq)/32
  dim3 g1(M / 128, DD / 128, 1);
  mfma_gemm<0><<<g1, 256, 0, stream>>>(inp, nullptr, WkHi, WkLo, bk, 1.0f, Kf, DD, 0, 0, 0);
  mfma_gemm<0><<<g1, 256, 0, stream>>>(inp, nullptr, WqHi, WqLo, bq, 0.03125f, Qf, DD, 0, 0, 0);

  // f_i = inp @ Wr^T + br
  root_kernel<<<M / 4, 256, 0, stream>>>(inp, Wr, br, f);

  // A[b,t,s] = (t==s)?0:exp(Q[b,t,:].K[b,s,:])
  dim3 g2(TT / 128, TT / 128, BB);
  mfma_gemm<1><<<g2, 256, 0, stream>>>(Qf, Kf, nullptr, nullptr, nullptr, 1.0f, A, TT,
                                       (long long)TT * DD, (long long)TT * DD,
                                       (long long)TT * TT);

  colsum_kernel<<<BB, TT, 0, stream>>>(A, cs);
  buildL_kernel<<<BB * TT, TT, 0, stream>>>(A, cs, f, L);

  gj_kernel<<<BB, 1024, 0, stream>>>(L);

  out_kernel<<<BB * TT, TT, 0, stream>>>(A, L, f, out);
}

// Round 4
// 890.213 us; speedup vs baseline: 26.1682x; 1.2697x over previous
//
#include <hip/hip_runtime.h>
#include <hip/hip_bf16.h>
#include <math.h>

#define BB 48
#define TT 256
#define DD 1024
#define BK 32

typedef __attribute__((ext_vector_type(8))) short bf16x8;
typedef __attribute__((ext_vector_type(8))) unsigned short ushortx8;
typedef __attribute__((ext_vector_type(4))) float f32x4;
typedef unsigned short u16;

__device__ __forceinline__ u16 bfb(float x) {
  __hip_bfloat16 h = __float2bfloat16(x);   // RNE
  return __builtin_bit_cast(u16, h);
}
__device__ __forceinline__ float fromb(u16 u) {
  unsigned v = (unsigned)u << 16;
  return __builtin_bit_cast(float, v);
}
__device__ __forceinline__ void gl16(const void* g, void* l) {
  __builtin_amdgcn_global_load_lds((const __attribute__((address_space(1))) unsigned int*)g,
                                   (__attribute__((address_space(3))) unsigned int*)l, 16, 0, 0);
}

// split x -> hi bf16 + lo bf16 (for Wk, Wq; n multiple of 1024)
__global__ void split_kernel(const float* __restrict__ src, u16* __restrict__ hi,
                             u16* __restrict__ lo, int n) {
  int idx = blockIdx.x * blockDim.x + threadIdx.x;
  if (idx * 4 >= n) return;
  float4 v = ((const float4*)src)[idx];
  ushort4 h, l;
  h.x = bfb(v.x); l.x = bfb(v.x - fromb(h.x));
  h.y = bfb(v.y); l.y = bfb(v.y - fromb(h.y));
  h.z = bfb(v.z); l.z = bfb(v.z - fromb(h.z));
  h.w = bfb(v.w); l.w = bfb(v.w - fromb(h.w));
  ((ushort4*)hi)[idx] = h;
  ((ushort4*)lo)[idx] = l;
}

// Split-bf16 MFMA GEMM (verified round 3): C[m,n] = sum_k A[m,k]*B[n,k]
template<int MODE>
__global__ __launch_bounds__(256) void mfma_gemm(
    const float* __restrict__ Af, const float* __restrict__ Bf,
    const u16* __restrict__ Bhi_g, const u16* __restrict__ Blo_g,
    const float* __restrict__ bias, float scale, float* __restrict__ Cg,
    int Nsz, long long sA, long long sB, long long sC) {
  __shared__ char lds[49152];
  char* sAhi = lds;
  char* sAlo = lds + 8192;
  char* sBhi = lds + 16384;
  char* sBlo = (MODE == 0) ? lds + 32768 : lds + 24576;

  const int tid = threadIdx.x;
  const int m0 = blockIdx.x * 128, n0 = blockIdx.y * 128;
  const float* Ab = Af + (long long)blockIdx.z * sA;
  float*       Cb = Cg + (long long)blockIdx.z * sC;

  const int sr = tid >> 1, sh = (tid & 1) * 16;
  const float* aG = Ab + (long long)(m0 + sr) * DD + sh;

  float4 av[4], bv[4];
  const float* bG = nullptr;
  const u16* bg0 = nullptr;
  const u16* bl0 = nullptr;
  if (MODE == 0) {
    bg0 = Bhi_g + (long long)(n0 + (tid >> 2)) * DD + (tid & 3) * 8;
    bl0 = Blo_g + (long long)(n0 + (tid >> 2)) * DD + (tid & 3) * 8;
  } else {
    const float* Bb = Bf + (long long)blockIdx.z * sB;
    bG = Bb + (long long)(n0 + sr) * DD + sh;
  }

  const int lane = tid & 63, wid = tid >> 6;
  const int wr = wid >> 1, wc = wid & 1;
  const int fr = lane & 15, fq = lane >> 4;

  f32x4 acc[4][4] = {};

  {
    const float4* p = (const float4*)(aG);
    av[0] = p[0]; av[1] = p[1]; av[2] = p[2]; av[3] = p[3];
    if (MODE == 0) {
      gl16(bg0,            sBhi + tid * 16);
      gl16(bg0 + 64 * DD,  sBhi + tid * 16 + 4096);
      gl16(bl0,            sBlo + tid * 16);
      gl16(bl0 + 64 * DD,  sBlo + tid * 16 + 4096);
    } else {
      const float4* q = (const float4*)(bG);
      bv[0] = q[0]; bv[1] = q[1]; bv[2] = q[2]; bv[3] = q[3];
    }
  }

  const int NS = DD / BK;
  for (int s = 0; s < NS; ++s) {
    const int bb = (MODE == 0) ? ((s & 1) << 13) : 0;

    ushortx8 ah0, ah1, al0, al1, bh0, bh1, blo0, blo1;
    {
      const float* af = (const float*)av;
      #pragma unroll
      for (int e = 0; e < 8; ++e) {
        u16 h = bfb(af[e]);      ah0[e] = h; al0[e] = bfb(af[e] - fromb(h));
        u16 h2 = bfb(af[e + 8]); ah1[e] = h2; al1[e] = bfb(af[e + 8] - fromb(h2));
      }
      if (MODE == 1) {
        const float* bf = (const float*)bv;
        #pragma unroll
        for (int e = 0; e < 8; ++e) {
          u16 h = bfb(bf[e]);      bh0[e] = h; blo0[e] = bfb(bf[e] - fromb(h));
          u16 h2 = bfb(bf[e + 8]); bh1[e] = h2; blo1[e] = bfb(bf[e + 8] - fromb(h2));
        }
      }
    }

    __syncthreads();

    {
      *(ushortx8*)(sAhi + sr * 64 + sh * 2)      = ah0;
      *(ushortx8*)(sAhi + sr * 64 + sh * 2 + 16) = ah1;
      *(ushortx8*)(sAlo + sr * 64 + sh * 2)      = al0;
      *(ushortx8*)(sAlo + sr * 64 + sh * 2 + 16) = al1;
      if (MODE == 1) {
        *(ushortx8*)(sBhi + sr * 64 + sh * 2)      = bh0;
        *(ushortx8*)(sBhi + sr * 64 + sh * 2 + 16) = bh1;
        *(ushortx8*)(sBlo + sr * 64 + sh * 2)      = blo0;
        *(ushortx8*)(sBlo + sr * 64 + sh * 2 + 16) = blo1;
      }
    }

    __syncthreads();

    if (s + 1 < NS) {
      const float4* p = (const float4*)(aG + (s + 1) * BK);
      av[0] = p[0]; av[1] = p[1]; av[2] = p[2]; av[3] = p[3];
      if (MODE == 0) {
        const int nb = ((s + 1) & 1) << 13;
        gl16(bg0 + (s + 1) * BK,            sBhi + nb + tid * 16);
        gl16(bg0 + (s + 1) * BK + 64 * DD,  sBhi + nb + tid * 16 + 4096);
        gl16(bl0 + (s + 1) * BK,            sBlo + nb + tid * 16);
        gl16(bl0 + (s + 1) * BK + 64 * DD,  sBlo + nb + tid * 16 + 4096);
      } else {
        const float4* q = (const float4*)(bG + (s + 1) * BK);
        bv[0] = q[0]; bv[1] = q[1]; bv[2] = q[2]; bv[3] = q[3];
      }
    }

    bf16x8 fah[4], fal[4], fbh[4], fbl[4];
    #pragma unroll
    for (int im = 0; im < 4; ++im) {
      const int off = (wr * 64 + im * 16 + fr) * 64 + fq * 16;
      fah[im] = *(const bf16x8*)(sAhi + off);
      fal[im] = *(const bf16x8*)(sAlo + off);
    }
    #pragma unroll
    for (int jn = 0; jn < 4; ++jn) {
      const int off = (wc * 64 + jn * 16 + fr) * 64 + fq * 16;
      fbh[jn] = *(const bf16x8*)(sBhi + bb + off);
      fbl[jn] = *(const bf16x8*)(sBlo + bb + off);
    }
    #pragma unroll
    for (int im = 0; im < 4; ++im)
      #pragma unroll
      for (int jn = 0; jn < 4; ++jn) {
        acc[im][jn] = __builtin_amdgcn_mfma_f32_16x16x32_bf16(fah[im], fbh[jn], acc[im][jn], 0, 0, 0);
        acc[im][jn] = __builtin_amdgcn_mfma_f32_16x16x32_bf16(fah[im], fbl[jn], acc[im][jn], 0, 0, 0);
        acc[im][jn] = __builtin_amdgcn_mfma_f32_16x16x32_bf16(fal[im], fbh[jn], acc[im][jn], 0, 0, 0);
      }
  }

  #pragma unroll
  for (int im = 0; im < 4; ++im) {
    #pragma unroll
    for (int jn = 0; jn < 4; ++jn) {
      const int mbase = m0 + wr * 64 + im * 16 + fq * 4;
      const int n     = n0 + wc * 64 + jn * 16 + fr;
      #pragma unroll
      for (int reg = 0; reg < 4; ++reg) {
        const int m = mbase + reg;
        float v = acc[im][jn][reg];
        if (MODE == 0) {
          v = (v + bias[n]) * scale;
        } else {
          v = expf(v);
          if (m == n) v = 0.f;
        }
        Cb[(long long)m * Nsz + n] = v;
      }
    }
  }
}

__global__ void root_kernel(const float* __restrict__ inp, const float* __restrict__ Wr,
                            const float* __restrict__ br, float* __restrict__ f) {
  int wave = threadIdx.x >> 6, lane = threadIdx.x & 63;
  int row = blockIdx.x * 4 + wave;
  const float* r = inp + (long long)row * DD;
  float s = 0.f;
  #pragma unroll
  for (int q = 0; q < DD / 64; ++q) s += r[lane + q * 64] * Wr[lane + q * 64];
  #pragma unroll
  for (int off = 32; off; off >>= 1) s += __shfl_down(s, off);
  if (lane == 0) f[row] = s + br[0];
}

__global__ void colsum_kernel(const float* __restrict__ Aall, float* __restrict__ cs) {
  int b = blockIdx.x, j = threadIdx.x;
  const float* Ab = Aall + (long long)b * TT * TT;
  float s = 0.f;
  for (int i = 0; i < TT; ++i) s += Ab[i * TT + j];
  cs[b * TT + j] = s;
}

__global__ void buildL_kernel(const float* __restrict__ Aall, const float* __restrict__ cs,
                              const float* __restrict__ f, float* __restrict__ L) {
  int bi = blockIdx.x;
  int b = bi >> 8, i = bi & 255, j = threadIdx.x;
  float v;
  if (i == 0) v = f[b * TT + j];
  else {
    v = -Aall[(long long)bi * TT + j];
    if (i == j) v += cs[b * TT + j];
  }
  L[(long long)bi * TT + j] = v;
}

// ---------------- blocked Gauss-Jordan inverse ----------------
// LDS byte offsets (total 151552 = 148 KB dynamic)
#define OFF_CHI 0          // u16 [256][40]  split(-C) hi
#define OFF_CLO 20480      // u16 [256][40]  split(-C) lo
#define OFF_RTH 40960      // u16 [256][40]  RpB^T hi   ([col][t])
#define OFF_RTL 61440      // u16 [256][40]  RpB^T lo
#define OFF_UT  81920      // f32 [256][68]  U^T chunk (64 rows)   } aliased
#define OFF_RFT 81920      // f32 [256][33]  R^T panel ([col][t])  } region
#define OFF_DHI 115712     // u16 [32][40]   split(Dinv) hi        }
#define OFF_DLO 118272     // u16 [32][40]   split(Dinv) lo        }
#define GJ_LDS  151552

// 32x32 Gauss-Jordan inverse held in one wave's registers.
// lane = 32*h + rl owns D[rl][h*16 .. h*16+15] in d[0..15].
// ZLAST: pivot order 1..31,0 (for the panel containing the root row).
template<bool ZLAST>
__device__ __forceinline__ void gj32(float* d, int rl, int h) {
  #pragma unroll
  for (int s = 0; s < 32; ++s) {
    const int t = ZLAST ? ((s + 1) & 31) : s;
    const int tl = t & 15, th = t >> 4;
    float rowv[16];
    #pragma unroll
    for (int j = 0; j < 16; ++j) rowv[j] = __shfl(d[j], t + 32 * h);
    const float pv   = __shfl(d[tl], t + 32 * th);
    const float colv = __shfl(d[tl], rl + 32 * th);
    const float ip = 1.0f / pv;
    if (rl == t) {
      #pragma unroll
      for (int j = 0; j < 16; ++j) {
        float v = rowv[j] * ip;
        if (j == tl) v = (h == th) ? ip : v;
        d[j] = v;
      }
    } else {
      const float cip = colv * ip;
      #pragma unroll
      for (int j = 0; j < 16; ++j) {
        float v = fmaf(-cip, rowv[j], d[j]);
        if (j == tl) v = (h == th) ? -cip : v;
        d[j] = v;
      }
    }
  }
}

// One 1024-thread block per matrix. Matrix fp32 in registers (thread tid owns
// row i=tid>>2, 64-col chunk c=tid&3). 8 panels of 32 pivots; per panel:
//  1. extract R^T (fp32) and split(-C) to LDS
//  2. wave 0: Dinv (32x32) via register/shfl GJ (no barriers), export split(Dinv)
//     and RpB^T pivot columns (= split(Dinv + I))
//  3. all waves: Rp = Dinv @ R via MFMA (split-bf16), store RpB^T split
//  4. pivot rows overwritten from RpB^T (-I on diagonal)
//  5. 4 chunks of 64 rows: U = (-C) @ RpB via MFMA -> UT in LDS -> r[] += U
// Panel order 1..7 then 0; within panel 0, local order 1..31,0 (root row last).
__global__ __launch_bounds__(1024) void gj_blocked(float* __restrict__ Lall) {
  extern __shared__ char lds[];
  float* Mb = Lall + (long long)blockIdx.x * TT * TT;
  const int tid = threadIdx.x;
  const int i = tid >> 2, c = tid & 3, jb = c * 64;
  const int wid = tid >> 6, lane = tid & 63;
  const int fr = lane & 15, fq = lane >> 4;

  float r[64];
  {
    const float4* src = (const float4*)(Mb + (long long)i * TT + jb);
    #pragma unroll
    for (int q = 0; q < 16; ++q) {
      float4 v = src[q];
      r[4*q+0] = v.x; r[4*q+1] = v.y; r[4*q+2] = v.z; r[4*q+3] = v.w;
    }
  }

  for (int pi = 0; pi < 8; ++pi) {
    const int p = (pi + 1) & 7;     // panels 1..7 then 0
    const int P0 = p * 32;

    // ---- step 1: extraction
    if ((i >> 5) == p) {            // pivot-row threads: R^T[col][t] fp32
      #pragma unroll
      for (int jj = 0; jj < 64; ++jj)
        *(float*)(lds + OFF_RFT + ((jb + jj) * 33 + (i - P0)) * 4) = r[jj];
    }
    if (c == (p >> 1)) {            // pivot-col threads: split(-C)[row][t]
      #pragma unroll
      for (int t = 0; t < 32; t += 2) {
        float v0 = (p & 1) ? -r[32 + t]     : -r[t];
        float v1 = (p & 1) ? -r[32 + t + 1] : -r[t + 1];
        u16 h0 = bfb(v0), h1 = bfb(v1);
        ushort2 hh; hh.x = h0; hh.y = h1;
        ushort2 ll; ll.x = bfb(v0 - fromb(h0)); ll.y = bfb(v1 - fromb(h1));
        *(ushort2*)(lds + OFF_CHI + (i * 40 + t) * 2) = hh;
        *(ushort2*)(lds + OFF_CLO + (i * 40 + t) * 2) = ll;
      }
    }
    __syncthreads();

    // ---- step 2: wave 0 computes Dinv in registers
    if (wid == 0) {
      const int rl = lane & 31, h = lane >> 5;
      float d[16];
      #pragma unroll
      for (int j = 0; j < 16; ++j)
        d[j] = *(const float*)(lds + OFF_RFT + ((P0 + h * 16 + j) * 33 + rl) * 4);
      if (p == 0) gj32<true>(d, rl, h); else gj32<false>(d, rl, h);
      // export split(Dinv) [row][col] for step-3 A operand
      #pragma unroll
      for (int j = 0; j < 16; j += 2) {
        u16 h0 = bfb(d[j]), h1 = bfb(d[j + 1]);
        ushort2 hh; hh.x = h0; hh.y = h1;
        ushort2 ll; ll.x = bfb(d[j] - fromb(h0)); ll.y = bfb(d[j + 1] - fromb(h1));
        *(ushort2*)(lds + OFF_DHI + (rl * 40 + h * 16 + j) * 2) = hh;
        *(ushort2*)(lds + OFF_DLO + (rl * 40 + h * 16 + j) * 2) = ll;
      }
      // export RpB^T pivot columns: RT[P0+t2][t=rl] = split(Dinv[rl][t2] + (rl==t2))
      #pragma unroll
      for (int j = 0; j < 16; ++j) {
        const int t2 = h * 16 + j;
        float v = d[j] + ((rl == t2) ? 1.0f : 0.0f);
        u16 hh = bfb(v);
        *(u16*)(lds + OFF_RTH + ((P0 + t2) * 40 + rl) * 2) = hh;
        *(u16*)(lds + OFF_RTL + ((P0 + t2) * 40 + rl) * 2) = bfb(v - fromb(hh));
      }
    }
    __syncthreads();

    // ---- step 3: Rp = Dinv @ R via MFMA; store RpB^T split (out columns)
    if ((wid >> 1) != p) {          // skip pivot-column strips (done by wave 0)
      const int col = wid * 16 + fr;
      ushortx8 bhu, blu;
      #pragma unroll
      for (int e = 0; e < 8; ++e) {
        float bv = *(const float*)(lds + OFF_RFT + (col * 33 + fq * 8 + e) * 4);
        u16 hh = bfb(bv);
        bhu[e] = hh; blu[e] = bfb(bv - fromb(hh));
      }
      const bf16x8 bh = __builtin_bit_cast(bf16x8, bhu);
      const bf16x8 bl = __builtin_bit_cast(bf16x8, blu);
      f32x4 acc2[2] = {};
      #pragma unroll
      for (int fi = 0; fi < 2; ++fi) {
        const bf16x8 ah = *(const bf16x8*)(lds + OFF_DHI + ((fi * 16 + fr) * 40 + fq * 8) * 2);
        const bf16x8 al = *(const bf16x8*)(lds + OFF_DLO + ((fi * 16 + fr) * 40 + fq * 8) * 2);
        acc2[fi] = __builtin_amdgcn_mfma_f32_16x16x32_bf16(ah, bh, acc2[fi], 0, 0, 0);
        acc2[fi] = __builtin_amdgcn_mfma_f32_16x16x32_bf16(ah, bl, acc2[fi], 0, 0, 0);
        acc2[fi] = __builtin_amdgcn_mfma_f32_16x16x32_bf16(al, bh, acc2[fi], 0, 0, 0);
      }
      #pragma unroll
      for (int fi = 0; fi < 2; ++fi) {
        ushort4 hh, ll;
        u16* hp = (u16*)&hh; u16* lp = (u16*)&ll;
        #pragma unroll
        for (int reg = 0; reg < 4; ++reg) {
          float v = acc2[fi][reg];
          u16 h0 = bfb(v);
          hp[reg] = h0; lp[reg] = bfb(v - fromb(h0));
        }
        *(ushort4*)(lds + OFF_RTH + (col * 40 + fi * 16 + fq * 4) * 2) = hh;
        *(ushort4*)(lds + OFF_RTL + (col * 40 + fi * 16 + fq * 4) * 2) = ll;
      }
    }
    __syncthreads();

    // ---- step 3.5: overwrite pivot rows from RpB^T (minus I on pivot diagonal)
    if ((i >> 5) == p) {
      #pragma unroll
      for (int jj = 0; jj < 64; ++jj) {
        const int colg = jb + jj;
        float v = fromb(*(const u16*)(lds + OFF_RTH + (colg * 40 + (i - P0)) * 2))
                + fromb(*(const u16*)(lds + OFF_RTL + (colg * 40 + (i - P0)) * 2));
        if (colg == i) v -= 1.0f;
        r[jj] = v;
      }
    }

    // ---- step 4: chunks of 64 rows: U = (-C) @ RpB -> UT -> r[] += U
    for (int ch = 0; ch < 4; ++ch) {
      const int r0 = ch * 64;
      const int frb = (wid >> 3) * 2;   // frag-row base (2 of 4)
      const int stb = (wid & 7) * 2;    // col-strip base (2 of 16)
      f32x4 acc[2][2] = {};
      bf16x8 Bh[2], Bl[2];
      #pragma unroll
      for (int dj = 0; dj < 2; ++dj) {
        const int col = (stb + dj) * 16 + fr;
        Bh[dj] = *(const bf16x8*)(lds + OFF_RTH + (col * 40 + fq * 8) * 2);
        Bl[dj] = *(const bf16x8*)(lds + OFF_RTL + (col * 40 + fq * 8) * 2);
      }
      #pragma unroll
      for (int di = 0; di < 2; ++di) {
        const int row = r0 + (frb + di) * 16 + fr;
        const bf16x8 Ah = *(const bf16x8*)(lds + OFF_CHI + (row * 40 + fq * 8) * 2);
        const bf16x8 Al = *(const bf16x8*)(lds + OFF_CLO + (row * 40 + fq * 8) * 2);
        #pragma unroll
        for (int dj = 0; dj < 2; ++dj) {
          acc[di][dj] = __builtin_amdgcn_mfma_f32_16x16x32_bf16(Ah, Bh[dj], acc[di][dj], 0, 0, 0);
          acc[di][dj] = __builtin_amdgcn_mfma_f32_16x16x32_bf16(Ah, Bl[dj], acc[di][dj], 0, 0, 0);
          acc[di][dj] = __builtin_amdgcn_mfma_f32_16x16x32_bf16(Al, Bh[dj], acc[di][dj], 0, 0, 0);
        }
      }
      #pragma unroll
      for (int di = 0; di < 2; ++di)
        #pragma unroll
        for (int dj = 0; dj < 2; ++dj) {
          float4 w;
          w.x = acc[di][dj][0]; w.y = acc[di][dj][1];
          w.z = acc[di][dj][2]; w.w = acc[di][dj][3];
          *(float4*)(lds + OFF_UT + (((stb + dj) * 16 + fr) * 68 + (frb + di) * 16 + fq * 4) * 4) = w;
        }
      __syncthreads();
      if (i >= r0 && i < r0 + 64 && (i >> 5) != p) {
        #pragma unroll
        for (int jj = 0; jj < 64; ++jj)
          r[jj] += *(const float*)(lds + OFF_UT + ((jb + jj) * 68 + (i - r0)) * 4);
      }
      __syncthreads();
    }
  }

  {
    float4* dst = (float4*)(Mb + (long long)i * TT + jb);
    #pragma unroll
    for (int q = 0; q < 16; ++q)
      dst[q] = make_float4(r[4*q], r[4*q+1], r[4*q+2], r[4*q+3]);
  }
}

__global__ void out_kernel(const float* __restrict__ Aall, const float* __restrict__ Linv,
                           const float* __restrict__ f, float* __restrict__ out) {
  int bj = blockIdx.x;
  int b = bj >> 8, j = bj & 255;
  const float* Lrow = Linv + (long long)b * TT * TT + j * TT;
  const float* Ab   = Aall + (long long)b * TT * TT;
  float fbj = f[bj];
  float dg = Lrow[j];
  float l0 = Lrow[0];
  float* orow = out + (long long)bj * (TT + 1);
  for (int c = threadIdx.x; c < TT + 1; c += 256) {
    float v;
    if (c == 0) v = fbj * l0;
    else {
      int i = c - 1;
      float aij = Ab[i * TT + j];
      float t1 = (j > 0) ? dg : 0.f;
      float t2 = (i > 0) ? Lrow[i] : 0.f;
      v = aij * (t1 - t2);
    }
    orow[c] = v;
  }
}

extern "C" void kernel_launch(void* const* d_in, const int* in_sizes, int n_in,
                              void* d_out, int out_size, void* d_ws, size_t ws_size,
                              hipStream_t stream) {
  const float* inp = (const float*)d_in[0];
  const float* Wk  = (const float*)d_in[1];
  const float* bk  = (const float*)d_in[2];
  const float* Wq  = (const float*)d_in[3];
  const float* bq  = (const float*)d_in[4];
  const float* Wr  = (const float*)d_in[5];
  const float* br  = (const float*)d_in[6];
  float* out = (float*)d_out;

  float* ws = (float*)d_ws;
  const long long NI = (long long)BB * TT * DD;
  float* Qf = ws;
  float* Kf = Qf + NI;
  float* A  = Kf + NI;
  float* f  = A + (long long)BB * TT * TT;
  float* cs = f + BB * TT;
  u16* WkHi = (u16*)(cs + BB * TT);
  u16* WkLo = WkHi + (long long)DD * DD;
  u16* WqHi = WkLo + (long long)DD * DD;
  u16* WqLo = WqHi + (long long)DD * DD;
  float* L = ws;   // aliases Qf (dead after einsum)

  const int M = BB * TT;

  static int lds_attr_set = 0;
  (void)hipFuncSetAttribute(reinterpret_cast<const void*>(gj_blocked),
                            hipFuncAttributeMaxDynamicSharedMemorySize, GJ_LDS);
  (void)lds_attr_set;

  split_kernel<<<DD * DD / 4 / 256, 256, 0, stream>>>(Wk, WkHi, WkLo, DD * DD);
  split_kernel<<<DD * DD / 4 / 256, 256, 0, stream>>>(Wq, WqHi, WqLo, DD * DD);

  dim3 g1(M / 128, DD / 128, 1);
  mfma_gemm<0><<<g1, 256, 0, stream>>>(inp, nullptr, WkHi, WkLo, bk, 1.0f, Kf, DD, 0, 0, 0);
  mfma_gemm<0><<<g1, 256, 0, stream>>>(inp, nullptr, WqHi, WqLo, bq, 0.03125f, Qf, DD, 0, 0, 0);

  root_kernel<<<M / 4, 256, 0, stream>>>(inp, Wr, br, f);

  dim3 g2(TT / 128, TT / 128, BB);
  mfma_gemm<1><<<g2, 256, 0, stream>>>(Qf, Kf, nullptr, nullptr, nullptr, 1.0f, A, TT,
                                       (long long)TT * DD, (long long)TT * DD,
                                       (long long)TT * TT);

  colsum_kernel<<<BB, TT, 0, stream>>>(A, cs);
  buildL_kernel<<<BB * TT, TT, 0, stream>>>(A, cs, f, L);

  gj_blocked<<<BB, 1024, GJ_LDS, stream>>>(L);

  out_kernel<<<BB * TT, TT, 0, stream>>>(A, L, f, out);
}

// Round 5
// 515.624 us; speedup vs baseline: 45.1788x; 1.7265x over previous
//
#include <hip/hip_runtime.h>
#include <hip/hip_bf16.h>
#include <math.h>

#define BB 48
#define TT 256
#define DD 1024
#define BK 32
#define NB 32

typedef __attribute__((ext_vector_type(8))) short bf16x8;
typedef __attribute__((ext_vector_type(8))) unsigned short ushortx8;
typedef __attribute__((ext_vector_type(4))) float f32x4;
typedef unsigned short u16;

__device__ __forceinline__ u16 bfb(float x) {
  __hip_bfloat16 h = __float2bfloat16(x);   // RNE
  return __builtin_bit_cast(u16, h);
}
__device__ __forceinline__ float fromb(u16 u) {
  unsigned v = (unsigned)u << 16;
  return __builtin_bit_cast(float, v);
}
__device__ __forceinline__ void gl16(const void* g, void* l) {
  __builtin_amdgcn_global_load_lds((const __attribute__((address_space(1))) unsigned int*)g,
                                   (__attribute__((address_space(3))) unsigned int*)l, 16, 0, 0);
}

// split x -> hi bf16 + lo bf16 (for Wk, Wq)
__global__ void split_kernel(const float* __restrict__ src, u16* __restrict__ hi,
                             u16* __restrict__ lo, int n) {
  int idx = blockIdx.x * blockDim.x + threadIdx.x;
  if (idx * 4 >= n) return;
  float4 v = ((const float4*)src)[idx];
  ushort4 h, l;
  h.x = bfb(v.x); l.x = bfb(v.x - fromb(h.x));
  h.y = bfb(v.y); l.y = bfb(v.y - fromb(h.y));
  h.z = bfb(v.z); l.z = bfb(v.z - fromb(h.z));
  h.w = bfb(v.w); l.w = bfb(v.w - fromb(h.w));
  ((ushort4*)hi)[idx] = h;
  ((ushort4*)lo)[idx] = l;
}

// Split-bf16 MFMA GEMM (verified round 3): C[m,n] = sum_k A[m,k]*B[n,k]
template<int MODE>
__global__ __launch_bounds__(256) void mfma_gemm(
    const float* __restrict__ Af, const float* __restrict__ Bf,
    const u16* __restrict__ Bhi_g, const u16* __restrict__ Blo_g,
    const float* __restrict__ bias, float scale, float* __restrict__ Cg,
    int Nsz, long long sA, long long sB, long long sC) {
  __shared__ char lds[49152];
  char* sAhi = lds;
  char* sAlo = lds + 8192;
  char* sBhi = lds + 16384;
  char* sBlo = (MODE == 0) ? lds + 32768 : lds + 24576;

  const int tid = threadIdx.x;
  const int m0 = blockIdx.x * 128, n0 = blockIdx.y * 128;
  const float* Ab = Af + (long long)blockIdx.z * sA;
  float*       Cb = Cg + (long long)blockIdx.z * sC;

  const int sr = tid >> 1, sh = (tid & 1) * 16;
  const float* aG = Ab + (long long)(m0 + sr) * DD + sh;

  float4 av[4], bv[4];
  const float* bG = nullptr;
  const u16* bg0 = nullptr;
  const u16* bl0 = nullptr;
  if (MODE == 0) {
    bg0 = Bhi_g + (long long)(n0 + (tid >> 2)) * DD + (tid & 3) * 8;
    bl0 = Blo_g + (long long)(n0 + (tid >> 2)) * DD + (tid & 3) * 8;
  } else {
    const float* Bb = Bf + (long long)blockIdx.z * sB;
    bG = Bb + (long long)(n0 + sr) * DD + sh;
  }

  const int lane = tid & 63, wid = tid >> 6;
  const int wr = wid >> 1, wc = wid & 1;
  const int fr = lane & 15, fq = lane >> 4;

  f32x4 acc[4][4] = {};

  {
    const float4* p = (const float4*)(aG);
    av[0] = p[0]; av[1] = p[1]; av[2] = p[2]; av[3] = p[3];
    if (MODE == 0) {
      gl16(bg0,            sBhi + tid * 16);
      gl16(bg0 + 64 * DD,  sBhi + tid * 16 + 4096);
      gl16(bl0,            sBlo + tid * 16);
      gl16(bl0 + 64 * DD,  sBlo + tid * 16 + 4096);
    } else {
      const float4* q = (const float4*)(bG);
      bv[0] = q[0]; bv[1] = q[1]; bv[2] = q[2]; bv[3] = q[3];
    }
  }

  const int NS = DD / BK;
  for (int s = 0; s < NS; ++s) {
    const int bb = (MODE == 0) ? ((s & 1) << 13) : 0;

    ushortx8 ah0, ah1, al0, al1, bh0, bh1, blo0, blo1;
    {
      const float* af = (const float*)av;
      #pragma unroll
      for (int e = 0; e < 8; ++e) {
        u16 h = bfb(af[e]);      ah0[e] = h; al0[e] = bfb(af[e] - fromb(h));
        u16 h2 = bfb(af[e + 8]); ah1[e] = h2; al1[e] = bfb(af[e + 8] - fromb(h2));
      }
      if (MODE == 1) {
        const float* bf = (const float*)bv;
        #pragma unroll
        for (int e = 0; e < 8; ++e) {
          u16 h = bfb(bf[e]);      bh0[e] = h; blo0[e] = bfb(bf[e] - fromb(h));
          u16 h2 = bfb(bf[e + 8]); bh1[e] = h2; blo1[e] = bfb(bf[e + 8] - fromb(h2));
        }
      }
    }

    __syncthreads();

    {
      *(ushortx8*)(sAhi + sr * 64 + sh * 2)      = ah0;
      *(ushortx8*)(sAhi + sr * 64 + sh * 2 + 16) = ah1;
      *(ushortx8*)(sAlo + sr * 64 + sh * 2)      = al0;
      *(ushortx8*)(sAlo + sr * 64 + sh * 2 + 16) = al1;
      if (MODE == 1) {
        *(ushortx8*)(sBhi + sr * 64 + sh * 2)      = bh0;
        *(ushortx8*)(sBhi + sr * 64 + sh * 2 + 16) = bh1;
        *(ushortx8*)(sBlo + sr * 64 + sh * 2)      = blo0;
        *(ushortx8*)(sBlo + sr * 64 + sh * 2 + 16) = blo1;
      }
    }

    __syncthreads();

    if (s + 1 < NS) {
      const float4* p = (const float4*)(aG + (s + 1) * BK);
      av[0] = p[0]; av[1] = p[1]; av[2] = p[2]; av[3] = p[3];
      if (MODE == 0) {
        const int nb = ((s + 1) & 1) << 13;
        gl16(bg0 + (s + 1) * BK,            sBhi + nb + tid * 16);
        gl16(bg0 + (s + 1) * BK + 64 * DD,  sBhi + nb + tid * 16 + 4096);
        gl16(bl0 + (s + 1) * BK,            sBlo + nb + tid * 16);
        gl16(bl0 + (s + 1) * BK + 64 * DD,  sBlo + nb + tid * 16 + 4096);
      } else {
        const float4* q = (const float4*)(bG + (s + 1) * BK);
        bv[0] = q[0]; bv[1] = q[1]; bv[2] = q[2]; bv[3] = q[3];
      }
    }

    bf16x8 fah[4], fal[4], fbh[4], fbl[4];
    #pragma unroll
    for (int im = 0; im < 4; ++im) {
      const int off = (wr * 64 + im * 16 + fr) * 64 + fq * 16;
      fah[im] = *(const bf16x8*)(sAhi + off);
      fal[im] = *(const bf16x8*)(sAlo + off);
    }
    #pragma unroll
    for (int jn = 0; jn < 4; ++jn) {
      const int off = (wc * 64 + jn * 16 + fr) * 64 + fq * 16;
      fbh[jn] = *(const bf16x8*)(sBhi + bb + off);
      fbl[jn] = *(const bf16x8*)(sBlo + bb + off);
    }
    #pragma unroll
    for (int im = 0; im < 4; ++im)
      #pragma unroll
      for (int jn = 0; jn < 4; ++jn) {
        acc[im][jn] = __builtin_amdgcn_mfma_f32_16x16x32_bf16(fah[im], fbh[jn], acc[im][jn], 0, 0, 0);
        acc[im][jn] = __builtin_amdgcn_mfma_f32_16x16x32_bf16(fah[im], fbl[jn], acc[im][jn], 0, 0, 0);
        acc[im][jn] = __builtin_amdgcn_mfma_f32_16x16x32_bf16(fal[im], fbh[jn], acc[im][jn], 0, 0, 0);
      }
  }

  #pragma unroll
  for (int im = 0; im < 4; ++im) {
    #pragma unroll
    for (int jn = 0; jn < 4; ++jn) {
      const int mbase = m0 + wr * 64 + im * 16 + fq * 4;
      const int n     = n0 + wc * 64 + jn * 16 + fr;
      #pragma unroll
      for (int reg = 0; reg < 4; ++reg) {
        const int m = mbase + reg;
        float v = acc[im][jn][reg];
        if (MODE == 0) {
          v = (v + bias[n]) * scale;
        } else {
          v = expf(v);
          if (m == n) v = 0.f;
        }
        Cb[(long long)m * Nsz + n] = v;
      }
    }
  }
}

__global__ void root_kernel(const float* __restrict__ inp, const float* __restrict__ Wr,
                            const float* __restrict__ br, float* __restrict__ f) {
  int wave = threadIdx.x >> 6, lane = threadIdx.x & 63;
  int row = blockIdx.x * 4 + wave;
  const float* r = inp + (long long)row * DD;
  float s = 0.f;
  #pragma unroll
  for (int q = 0; q < DD / 64; ++q) s += r[lane + q * 64] * Wr[lane + q * 64];
  #pragma unroll
  for (int off = 32; off; off >>= 1) s += __shfl_down(s, off);
  if (lane == 0) f[row] = s + br[0];
}

__global__ void colsum_kernel(const float* __restrict__ Aall, float* __restrict__ cs) {
  int b = blockIdx.x, j = threadIdx.x;
  const float* Ab = Aall + (long long)b * TT * TT;
  float s = 0.f;
  for (int i = 0; i < TT; ++i) s += Ab[i * TT + j];
  cs[b * TT + j] = s;
}

__global__ void buildL_kernel(const float* __restrict__ Aall, const float* __restrict__ cs,
                              const float* __restrict__ f, float* __restrict__ L) {
  int bi = blockIdx.x;
  int b = bi >> 8, i = bi & 255, j = threadIdx.x;
  float v;
  if (i == 0) v = f[b * TT + j];
  else {
    v = -Aall[(long long)bi * TT + j];
    if (i == j) v += cs[b * TT + j];
  }
  L[(long long)bi * TT + j] = v;
}

// 32x32 Gauss-Jordan inverse in one wave's registers (verified round 4).
// lane = 32*h + rl owns D[rl][h*16 .. h*16+15] in d[0..15].
template<bool ZLAST>
__device__ __forceinline__ void gj32(float* d, int rl, int h) {
  #pragma unroll
  for (int s = 0; s < 32; ++s) {
    const int t = ZLAST ? ((s + 1) & 31) : s;
    const int tl = t & 15, th = t >> 4;
    float rowv[16];
    #pragma unroll
    for (int j = 0; j < 16; ++j) rowv[j] = __shfl(d[j], t + 32 * h);
    const float pv   = __shfl(d[tl], t + 32 * th);
    const float colv = __shfl(d[tl], rl + 32 * th);
    const float ip = 1.0f / pv;
    if (rl == t) {
      #pragma unroll
      for (int j = 0; j < 16; ++j) {
        float v = rowv[j] * ip;
        if (j == tl) v = (h == th) ? ip : v;
        d[j] = v;
      }
    } else {
      const float cip = colv * ip;
      #pragma unroll
      for (int j = 0; j < 16; ++j) {
        float v = fmaf(-cip, rowv[j], d[j]);
        if (j == tl) v = (h == th) ? -cip : v;
        d[j] = v;
      }
    }
  }
}

// Panel prepare: for pivot set P = [P0, P0+32):
//  - stage R^T = M[P][:]^T split-bf16 in LDS; export split(-C) = -M[:][P] to staging
//  - wave 0: Dinv = inv(M[P][P]) via gj32
//  - Rp = Dinv @ R via MFMA; write M[P][:] = Rp (pivot block = Dinv) and
//    staging RpB^T[j][t] = split(Rp[t][j]), pivot cols = split(Dinv + I).
template<bool ZLAST>
__global__ __launch_bounds__(256) void panel_prep(float* __restrict__ Mg,
    u16* __restrict__ Ch, u16* __restrict__ Cl,
    u16* __restrict__ Rh, u16* __restrict__ Rl, int p) {
  __shared__ u16 RTh[256][40];
  __shared__ u16 RTl[256][40];
  __shared__ u16 Dh[32][40];
  __shared__ u16 Dl[32][40];
  const int b = blockIdx.x;
  float* M = Mg + (long long)b * TT * TT;
  const int tid = threadIdx.x;
  const int P0 = p * NB;
  const int wid = tid >> 6, lane = tid & 63;
  const int fr = lane & 15, fq = lane >> 4;

  // step 1a: stage R^T split. thread: R row sr = tid>>3, 32 cols from (tid&7)*32
  {
    const int sr = tid >> 3, sc0 = (tid & 7) * 32;
    const float4* src = (const float4*)(M + (long long)(P0 + sr) * TT + sc0);
    #pragma unroll
    for (int q = 0; q < 8; ++q) {
      float4 v = src[q];
      float vv[4] = {v.x, v.y, v.z, v.w};
      #pragma unroll
      for (int l = 0; l < 4; ++l) {
        const int j = sc0 + q * 4 + l;
        u16 h = bfb(vv[l]);
        RTh[j][sr] = h;
        RTl[j][sr] = bfb(vv[l] - fromb(h));
      }
    }
  }
  // step 1b: export split(-C). thread: row tid, cols P0..P0+31
  {
    const float4* src = (const float4*)(M + (long long)tid * TT + P0);
    u16 hbuf[32], lbuf[32];
    #pragma unroll
    for (int q = 0; q < 8; ++q) {
      float4 v = src[q];
      float vv[4] = {v.x, v.y, v.z, v.w};
      #pragma unroll
      for (int l = 0; l < 4; ++l) {
        float x = -vv[l];
        u16 h = bfb(x);
        hbuf[q * 4 + l] = h;
        lbuf[q * 4 + l] = bfb(x - fromb(h));
      }
    }
    ushort4* dh = (ushort4*)(Ch + ((long long)b * TT + tid) * NB);
    ushort4* dl = (ushort4*)(Cl + ((long long)b * TT + tid) * NB);
    #pragma unroll
    for (int q = 0; q < 8; ++q) {
      ushort4 oh, ol;
      oh.x = hbuf[q*4+0]; oh.y = hbuf[q*4+1]; oh.z = hbuf[q*4+2]; oh.w = hbuf[q*4+3];
      ol.x = lbuf[q*4+0]; ol.y = lbuf[q*4+1]; ol.z = lbuf[q*4+2]; ol.w = lbuf[q*4+3];
      dh[q] = oh; dl[q] = ol;
    }
  }
  __syncthreads();

  // step 2: wave 0 computes Dinv
  if (wid == 0) {
    const int rl = lane & 31, h2 = lane >> 5;
    float d[16];
    #pragma unroll
    for (int j = 0; j < 16; ++j) {
      const int col = P0 + h2 * 16 + j;
      d[j] = fromb(RTh[col][rl]) + fromb(RTl[col][rl]);
    }
    gj32<ZLAST>(d, rl, h2);
    #pragma unroll
    for (int j = 0; j < 16; ++j) {
      u16 hh = bfb(d[j]);
      Dh[rl][h2 * 16 + j] = hh;
      Dl[rl][h2 * 16 + j] = bfb(d[j] - fromb(hh));
    }
  }
  __syncthreads();

  // step 3: Rp = Dinv @ R (all 256 cols); write M pivot rows + RpB^T staging
  u16* Rbh = Rh + (long long)b * TT * NB;
  u16* Rbl = Rl + (long long)b * TT * NB;
  #pragma unroll
  for (int cf = 0; cf < 4; ++cf) {
    const int j = wid * 64 + cf * 16 + fr;
    const bf16x8 bh = *(const bf16x8*)&RTh[j][fq * 8];
    const bf16x8 bl = *(const bf16x8*)&RTl[j][fq * 8];
    const bool inP = ((unsigned)(j - P0)) < 32u;
    const int s = j - P0;
    #pragma unroll
    for (int fi = 0; fi < 2; ++fi) {
      const bf16x8 ah = *(const bf16x8*)&Dh[fi * 16 + fr][fq * 8];
      const bf16x8 al = *(const bf16x8*)&Dl[fi * 16 + fr][fq * 8];
      f32x4 acc = {};
      acc = __builtin_amdgcn_mfma_f32_16x16x32_bf16(ah, bh, acc, 0, 0, 0);
      acc = __builtin_amdgcn_mfma_f32_16x16x32_bf16(ah, bl, acc, 0, 0, 0);
      acc = __builtin_amdgcn_mfma_f32_16x16x32_bf16(al, bh, acc, 0, 0, 0);
      ushort4 oh, ol;
      u16* hp = (u16*)&oh; u16* lp = (u16*)&ol;
      float mvals[4];
      #pragma unroll
      for (int reg = 0; reg < 4; ++reg) {
        const int t = fi * 16 + fq * 4 + reg;
        float v = acc[reg];
        if (inP) v = fromb(Dh[t][s]) + fromb(Dl[t][s]);     // exact Dinv value
        mvals[reg] = v;                                      // -> M[P0+t][j]
        float rv = inP ? (v + ((t == s) ? 1.0f : 0.0f)) : v; // -> staging
        u16 hh = bfb(rv);
        hp[reg] = hh;
        lp[reg] = bfb(rv - fromb(hh));
      }
      *(ushort4*)(Rbh + (long long)j * NB + fi * 16 + fq * 4) = oh;
      *(ushort4*)(Rbl + (long long)j * NB + fi * 16 + fq * 4) = ol;
      #pragma unroll
      for (int reg = 0; reg < 4; ++reg)
        M[(long long)(P0 + fi * 16 + fq * 4 + reg) * TT + j] = mvals[reg];
    }
  }
}

// Panel update: M[i][:] += (-C[i]) @ RpB for i not in P (RMW; pivot cols get
// -(C@Dinv) automatically via the Dinv+I trick). Fragments straight from
// global staging (L2-hot) — no LDS. grid (4 row-chunks, 48 matrices).
__global__ __launch_bounds__(256) void panel_update(float* __restrict__ Mg,
    const u16* __restrict__ Ch, const u16* __restrict__ Cl,
    const u16* __restrict__ Rh, const u16* __restrict__ Rl, int p) {
  const int b = blockIdx.y;
  float* M = Mg + (long long)b * TT * TT;
  const u16* Cbh = Ch + (long long)b * TT * NB;
  const u16* Cbl = Cl + (long long)b * TT * NB;
  const u16* Rbh = Rh + (long long)b * TT * NB;
  const u16* Rbl = Rl + (long long)b * TT * NB;
  const int tid = threadIdx.x, wid = tid >> 6, lane = tid & 63;
  const int fr = lane & 15, fq = lane >> 4;
  const int r0 = blockIdx.x * 64 + wid * 16;   // this wave's 16 rows
  const int P0 = p * NB;

  const bf16x8 ah = *(const bf16x8*)(Cbh + (long long)(r0 + fr) * NB + fq * 8);
  const bf16x8 al = *(const bf16x8*)(Cbl + (long long)(r0 + fr) * NB + fq * 8);

  f32x4 acc[16];
  #pragma unroll
  for (int cf = 0; cf < 16; ++cf) {
    const int j = cf * 16 + fr;
    const bf16x8 bh = *(const bf16x8*)(Rbh + (long long)j * NB + fq * 8);
    const bf16x8 bl = *(const bf16x8*)(Rbl + (long long)j * NB + fq * 8);
    f32x4 a = {};
    a = __builtin_amdgcn_mfma_f32_16x16x32_bf16(ah, bh, a, 0, 0, 0);
    a = __builtin_amdgcn_mfma_f32_16x16x32_bf16(ah, bl, a, 0, 0, 0);
    a = __builtin_amdgcn_mfma_f32_16x16x32_bf16(al, bh, a, 0, 0, 0);
    acc[cf] = a;
  }
  #pragma unroll
  for (int reg = 0; reg < 4; ++reg) {
    const int m = r0 + fq * 4 + reg;
    if ((unsigned)(m - P0) < 32u) continue;    // pivot rows written by prep
    #pragma unroll
    for (int cf = 0; cf < 16; ++cf) {
      const int n = cf * 16 + fr;
      M[(long long)m * TT + n] += acc[cf][reg];
    }
  }
}

__global__ void out_kernel(const float* __restrict__ Aall, const float* __restrict__ Linv,
                           const float* __restrict__ f, float* __restrict__ out) {
  int bj = blockIdx.x;
  int b = bj >> 8, j = bj & 255;
  const float* Lrow = Linv + (long long)b * TT * TT + j * TT;
  const float* Ab   = Aall + (long long)b * TT * TT;
  float fbj = f[bj];
  float dg = Lrow[j];
  float l0 = Lrow[0];
  float* orow = out + (long long)bj * (TT + 1);
  for (int c = threadIdx.x; c < TT + 1; c += 256) {
    float v;
    if (c == 0) v = fbj * l0;
    else {
      int i = c - 1;
      float aij = Ab[i * TT + j];
      float t1 = (j > 0) ? dg : 0.f;
      float t2 = (i > 0) ? Lrow[i] : 0.f;
      v = aij * (t1 - t2);
    }
    orow[c] = v;
  }
}

extern "C" void kernel_launch(void* const* d_in, const int* in_sizes, int n_in,
                              void* d_out, int out_size, void* d_ws, size_t ws_size,
                              hipStream_t stream) {
  const float* inp = (const float*)d_in[0];
  const float* Wk  = (const float*)d_in[1];
  const float* bk  = (const float*)d_in[2];
  const float* Wq  = (const float*)d_in[3];
  const float* bq  = (const float*)d_in[4];
  const float* Wr  = (const float*)d_in[5];
  const float* br  = (const float*)d_in[6];
  float* out = (float*)d_out;

  // workspace (~124.9 MB; 126 MB proven available in round 1)
  float* ws = (float*)d_ws;
  const long long NI = (long long)BB * TT * DD;
  float* Qf = ws;
  float* Kf = Qf + NI;
  float* A  = Kf + NI;
  float* f  = A + (long long)BB * TT * TT;
  float* cs = f + BB * TT;
  u16* WkHi = (u16*)(cs + BB * TT);
  u16* WkLo = WkHi + (long long)DD * DD;
  u16* WqHi = WkLo + (long long)DD * DD;
  u16* WqLo = WqHi + (long long)DD * DD;
  u16* Csth = WqLo + (long long)DD * DD;          // [48][256][32]
  u16* Cstl = Csth + (long long)BB * TT * NB;
  u16* Rph  = Cstl + (long long)BB * TT * NB;
  u16* Rpl  = Rph  + (long long)BB * TT * NB;
  float* L = ws;   // aliases Qf (dead after einsum)

  const int M = BB * TT;

  split_kernel<<<DD * DD / 4 / 256, 256, 0, stream>>>(Wk, WkHi, WkLo, DD * DD);
  split_kernel<<<DD * DD / 4 / 256, 256, 0, stream>>>(Wq, WqHi, WqLo, DD * DD);

  dim3 g1(M / 128, DD / 128, 1);
  mfma_gemm<0><<<g1, 256, 0, stream>>>(inp, nullptr, WkHi, WkLo, bk, 1.0f, Kf, DD, 0, 0, 0);
  mfma_gemm<0><<<g1, 256, 0, stream>>>(inp, nullptr, WqHi, WqLo, bq, 0.03125f, Qf, DD, 0, 0, 0);

  root_kernel<<<M / 4, 256, 0, stream>>>(inp, Wr, br, f);

  dim3 g2(TT / 128, TT / 128, BB);
  mfma_gemm<1><<<g2, 256, 0, stream>>>(Qf, Kf, nullptr, nullptr, nullptr, 1.0f, A, TT,
                                       (long long)TT * DD, (long long)TT * DD,
                                       (long long)TT * TT);

  colsum_kernel<<<BB, TT, 0, stream>>>(A, cs);
  buildL_kernel<<<BB * TT, TT, 0, stream>>>(A, cs, f, L);

  // blocked Gauss-Jordan inverse: panels 1..7 then 0 (root row pivoted last)
  for (int pi = 0; pi < 8; ++pi) {
    const int p = (pi + 1) & 7;
    if (p == 0)
      panel_prep<true><<<BB, 256, 0, stream>>>(L, Csth, Cstl, Rph, Rpl, p);
    else
      panel_prep<false><<<BB, 256, 0, stream>>>(L, Csth, Cstl, Rph, Rpl, p);
    panel_update<<<dim3(4, BB), 256, 0, stream>>>(L, Csth, Cstl, Rph, Rpl, p);
  }

  out_kernel<<<BB * TT, TT, 0, stream>>>(A, L, f, out);
}

// Round 6
// 427.746 us; speedup vs baseline: 54.4605x; 1.2054x over previous
//
#include <hip/hip_runtime.h>
#include <hip/hip_bf16.h>
#include <math.h>

#define BB 48
#define TT 256
#define DD 1024
#define NB 32

typedef __attribute__((ext_vector_type(8))) short bf16x8;
typedef __attribute__((ext_vector_type(4))) float f32x4;
typedef unsigned short u16;

__device__ __forceinline__ u16 bfb(float x) {
  __hip_bfloat16 h = __float2bfloat16(x);   // RNE
  return __builtin_bit_cast(u16, h);
}
__device__ __forceinline__ float fromb(u16 u) {
  unsigned v = (unsigned)u << 16;
  return __builtin_bit_cast(float, v);
}
__device__ __forceinline__ void gl16(const void* g, void* l) {
  __builtin_amdgcn_global_load_lds((const __attribute__((address_space(1))) unsigned int*)g,
                                   (__attribute__((address_space(3))) unsigned int*)l, 16, 0, 0);
}

// split x -> hi bf16 + lo bf16
__global__ void split_kernel(const float* __restrict__ src, u16* __restrict__ hi,
                             u16* __restrict__ lo, int n) {
  int idx = blockIdx.x * blockDim.x + threadIdx.x;
  if (idx * 4 >= n) return;
  float4 v = ((const float4*)src)[idx];
  ushort4 h, l;
  h.x = bfb(v.x); l.x = bfb(v.x - fromb(h.x));
  h.y = bfb(v.y); l.y = bfb(v.y - fromb(h.y));
  h.z = bfb(v.z); l.z = bfb(v.z - fromb(h.z));
  h.w = bfb(v.w); l.w = bfb(v.w - fromb(h.w));
  ((ushort4*)hi)[idx] = h;
  ((ushort4*)lo)[idx] = l;
}

// Transpose + split: WT[d][n] = split(W[n][d]). grid (32,32,2), block (32,8).
__global__ void tsplit_kernel(const float* __restrict__ Wq, const float* __restrict__ Wk,
                              u16* __restrict__ WqTh, u16* __restrict__ WqTl,
                              u16* __restrict__ WkTh, u16* __restrict__ WkTl) {
  const float* W = blockIdx.z ? Wk : Wq;
  u16* Th = blockIdx.z ? WkTh : WqTh;
  u16* Tl = blockIdx.z ? WkTl : WqTl;
  __shared__ float t[32][33];
  const int tx = threadIdx.x, ty = threadIdx.y;
  const int x = blockIdx.x * 32 + tx;
  #pragma unroll
  for (int j = 0; j < 32; j += 8)
    t[ty + j][tx] = W[(long long)(blockIdx.y * 32 + ty + j) * DD + x];
  __syncthreads();
  const int n = blockIdx.y * 32 + tx;
  #pragma unroll
  for (int j = 0; j < 32; j += 8) {
    const int d = blockIdx.x * 32 + ty + j;
    float v = t[tx][ty + j];
    u16 h = bfb(v);
    Th[(long long)d * DD + n] = h;
    Tl[(long long)d * DD + n] = bfb(v - fromb(h));
  }
}

// c0f[0] = s * dot(bq, bk)
__global__ void c0_kernel(const float* __restrict__ bq, const float* __restrict__ bk,
                          float* __restrict__ c0f) {
  __shared__ float ws4[4];
  const int tid = threadIdx.x, lane = tid & 63, wave = tid >> 6;
  float s = 0.f;
  #pragma unroll
  for (int q = 0; q < 4; ++q) { int d = tid + q * 256; s += bq[d] * bk[d]; }
  #pragma unroll
  for (int off = 32; off; off >>= 1) s += __shfl_down(s, off);
  if (lane == 0) ws4[wave] = s;
  __syncthreads();
  if (tid == 0) c0f[0] = 0.03125f * (ws4[0] + ws4[1] + ws4[2] + ws4[3]);
}

// out[row] = dot(X[row], w) + (biasptr ? biasptr[0] : 0)
__global__ void rootv_kernel(const float* __restrict__ X, const float* __restrict__ w,
                             const float* __restrict__ biasptr, float* __restrict__ out) {
  const int wave = threadIdx.x >> 6, lane = threadIdx.x & 63;
  const int row = blockIdx.x * 4 + wave;
  const float* r = X + (long long)row * DD;
  float s = 0.f;
  #pragma unroll
  for (int q = 0; q < DD / 64; ++q) s += r[lane + q * 64] * w[lane + q * 64];
  #pragma unroll
  for (int off = 32; off; off >>= 1) s += __shfl_down(s, off);
  if (lane == 0) out[row] = s + (biasptr ? biasptr[0] : 0.0f);
}

// out[row] = scale * dot(hi[row]+lo[row], w)   (split-bf16 input rows, 1024 wide)
__global__ void rootv_split_kernel(const u16* __restrict__ Th, const u16* __restrict__ Tl,
                                   const float* __restrict__ w, float* __restrict__ out,
                                   float scale) {
  const int wave = threadIdx.x >> 6, lane = threadIdx.x & 63;
  const int row = blockIdx.x * 4 + wave;
  const u16* th = Th + (long long)row * DD;
  const u16* tl = Tl + (long long)row * DD;
  float s = 0.f;
  #pragma unroll
  for (int q = 0; q < DD / 64; ++q) {
    int d = lane + q * 64;
    s += (fromb(th[d]) + fromb(tl[d])) * w[d];
  }
  #pragma unroll
  for (int off = 32; off; off >>= 1) s += __shfl_down(s, off);
  if (lane == 0) out[row] = scale * s;
}

// Pre-split GEMM: C[m,n] = sum_k (Ah+Al)[m,k]*(Bh+Bl)[n,k], 3-term split-bf16 MFMA.
// All four operands staged via global_load_lds w16, double-buffered, one barrier
// per K-step (syncthreads' vmcnt/lgkmcnt drain covers in-flight gl_lds and the
// previous step's ds_reads). No VALU conversion anywhere in the loop.
// EPI 0: Ch/Cl = split(acc)            (HT gemm, Z gemm)
// EPI 1: Cf = exp(s*acc + spu[m]+spv[n]), zero diagonal   (einsum)
template<int EPI>
__global__ __launch_bounds__(256) void pg_kernel(
    const u16* __restrict__ Ah, const u16* __restrict__ Al,
    const u16* __restrict__ Bh, const u16* __restrict__ Bl,
    u16* __restrict__ Ch, u16* __restrict__ Cl, float* __restrict__ Cf,
    const float* __restrict__ spu, const float* __restrict__ spv,
    float sscale, int Kd, int Nsz,
    long long sA, long long sB, long long sC) {
  extern __shared__ char lds[];   // 2 x {Ahi,Alo,Bhi,Blo} x 8KB = 64 KB
  const int tid = threadIdx.x;
  const int m0 = blockIdx.x * 128, n0 = blockIdx.y * 128;
  const int z = blockIdx.z;
  const u16* Abh = Ah + (long long)z * sA;
  const u16* Abl = Al + (long long)z * sA;
  const u16* Bbh = Bh + (long long)z * sB;
  const u16* Bbl = Bl + (long long)z * sB;

  const int srow = tid >> 2;            // 0..63
  const int scol = (tid & 3) * 8;       // u16 offset (16B chunk)
  const u16* a0 = Abh + (long long)(m0 + srow) * Kd + scol;
  const u16* a1 = Abl + (long long)(m0 + srow) * Kd + scol;
  const u16* b0 = Bbh + (long long)(n0 + srow) * Kd + scol;
  const u16* b1 = Bbl + (long long)(n0 + srow) * Kd + scol;
  const long long half = (long long)64 * Kd;

  const int lane = tid & 63, wid = tid >> 6;
  const int wr = wid >> 1, wc = wid & 1;
  const int fr = lane & 15, fq = lane >> 4;

  f32x4 acc[4][4] = {};

  { // prologue: stage step 0 into buffer 0
    char* d = lds + tid * 16;
    gl16(a0, d);          gl16(a0 + half, d + 4096);
    gl16(a1, d + 8192);   gl16(a1 + half, d + 12288);
    gl16(b0, d + 16384);  gl16(b0 + half, d + 20480);
    gl16(b1, d + 24576);  gl16(b1 + half, d + 28672);
  }

  const int NS = Kd / 32;
  for (int s = 0; s < NS; ++s) {
    const int bb = (s & 1) << 15;
    __syncthreads();    // buf[s&1] landed; all waves' prior ds_reads drained

    if (s + 1 < NS) {   // stage next step into the other buffer (flies under MFMA)
      const int ko = (s + 1) * 32;
      char* d = lds + (((s + 1) & 1) << 15) + tid * 16;
      gl16(a0 + ko, d);          gl16(a0 + ko + half, d + 4096);
      gl16(a1 + ko, d + 8192);   gl16(a1 + ko + half, d + 12288);
      gl16(b0 + ko, d + 16384);  gl16(b0 + ko + half, d + 20480);
      gl16(b1 + ko, d + 24576);  gl16(b1 + ko + half, d + 28672);
    }

    const char* Ahs = lds + bb;
    const char* Als = lds + bb + 8192;
    const char* Bhs = lds + bb + 16384;
    const char* Bls = lds + bb + 24576;
    bf16x8 fah[4], fal[4], fbh[4], fbl[4];
    #pragma unroll
    for (int im = 0; im < 4; ++im) {
      const int off = (wr * 64 + im * 16 + fr) * 64 + fq * 16;
      fah[im] = *(const bf16x8*)(Ahs + off);
      fal[im] = *(const bf16x8*)(Als + off);
    }
    #pragma unroll
    for (int jn = 0; jn < 4; ++jn) {
      const int off = (wc * 64 + jn * 16 + fr) * 64 + fq * 16;
      fbh[jn] = *(const bf16x8*)(Bhs + off);
      fbl[jn] = *(const bf16x8*)(Bls + off);
    }
    #pragma unroll
    for (int im = 0; im < 4; ++im)
      #pragma unroll
      for (int jn = 0; jn < 4; ++jn) {
        acc[im][jn] = __builtin_amdgcn_mfma_f32_16x16x32_bf16(fah[im], fbh[jn], acc[im][jn], 0, 0, 0);
        acc[im][jn] = __builtin_amdgcn_mfma_f32_16x16x32_bf16(fah[im], fbl[jn], acc[im][jn], 0, 0, 0);
        acc[im][jn] = __builtin_amdgcn_mfma_f32_16x16x32_bf16(fal[im], fbh[jn], acc[im][jn], 0, 0, 0);
      }
  }

  // epilogue: C/D layout col=lane&15, row=(lane>>4)*4+reg  [verified rounds 3-5]
  #pragma unroll
  for (int im = 0; im < 4; ++im) {
    #pragma unroll
    for (int jn = 0; jn < 4; ++jn) {
      const int mbase = m0 + wr * 64 + im * 16 + fq * 4;
      const int n     = n0 + wc * 64 + jn * 16 + fr;
      #pragma unroll
      for (int reg = 0; reg < 4; ++reg) {
        const int m = mbase + reg;
        const float v = acc[im][jn][reg];
        if (EPI == 0) {
          u16 h = bfb(v);
          Ch[(long long)z * sC + (long long)m * Nsz + n] = h;
          Cl[(long long)z * sC + (long long)m * Nsz + n] = bfb(v - fromb(h));
        } else {
          float e = expf(fmaf(sscale, v, spu[z * TT + m] + spv[z * TT + n]));
          if (m == n) e = 0.f;
          Cf[(long long)z * sC + (long long)m * Nsz + n] = e;
        }
      }
    }
  }
}

__global__ void colsum_kernel(const float* __restrict__ Aall, float* __restrict__ cs) {
  int b = blockIdx.x, j = threadIdx.x;
  const float* Ab = Aall + (long long)b * TT * TT;
  float s = 0.f;
  for (int i = 0; i < TT; ++i) s += Ab[i * TT + j];
  cs[b * TT + j] = s;
}

__global__ void buildL_kernel(const float* __restrict__ Aall, const float* __restrict__ cs,
                              const float* __restrict__ f, float* __restrict__ L) {
  int bi = blockIdx.x;
  int b = bi >> 8, i = bi & 255, j = threadIdx.x;
  float v;
  if (i == 0) v = f[b * TT + j];
  else {
    v = -Aall[(long long)bi * TT + j];
    if (i == j) v += cs[b * TT + j];
  }
  L[(long long)bi * TT + j] = v;
}

// 32x32 Gauss-Jordan inverse in one wave's registers (verified round 4).
template<bool ZLAST>
__device__ __forceinline__ void gj32(float* d, int rl, int h) {
  #pragma unroll
  for (int s = 0; s < 32; ++s) {
    const int t = ZLAST ? ((s + 1) & 31) : s;
    const int tl = t & 15, th = t >> 4;
    float rowv[16];
    #pragma unroll
    for (int j = 0; j < 16; ++j) rowv[j] = __shfl(d[j], t + 32 * h);
    const float pv   = __shfl(d[tl], t + 32 * th);
    const float colv = __shfl(d[tl], rl + 32 * th);
    const float ip = 1.0f / pv;
    if (rl == t) {
      #pragma unroll
      for (int j = 0; j < 16; ++j) {
        float v = rowv[j] * ip;
        if (j == tl) v = (h == th) ? ip : v;
        d[j] = v;
      }
    } else {
      const float cip = colv * ip;
      #pragma unroll
      for (int j = 0; j < 16; ++j) {
        float v = fmaf(-cip, rowv[j], d[j]);
        if (j == tl) v = (h == th) ? -cip : v;
        d[j] = v;
      }
    }
  }
}

// Panel prepare (verified round 5)
template<bool ZLAST>
__global__ __launch_bounds__(256) void panel_prep(float* __restrict__ Mg,
    u16* __restrict__ Ch, u16* __restrict__ Cl,
    u16* __restrict__ Rh, u16* __restrict__ Rl, int p) {
  __shared__ u16 RTh[256][40];
  __shared__ u16 RTl[256][40];
  __shared__ u16 Dh[32][40];
  __shared__ u16 Dl[32][40];
  const int b = blockIdx.x;
  float* M = Mg + (long long)b * TT * TT;
  const int tid = threadIdx.x;
  const int P0 = p * NB;
  const int wid = tid >> 6, lane = tid & 63;
  const int fr = lane & 15, fq = lane >> 4;

  {
    const int sr = tid >> 3, sc0 = (tid & 7) * 32;
    const float4* src = (const float4*)(M + (long long)(P0 + sr) * TT + sc0);
    #pragma unroll
    for (int q = 0; q < 8; ++q) {
      float4 v = src[q];
      float vv[4] = {v.x, v.y, v.z, v.w};
      #pragma unroll
      for (int l = 0; l < 4; ++l) {
        const int j = sc0 + q * 4 + l;
        u16 h = bfb(vv[l]);
        RTh[j][sr] = h;
        RTl[j][sr] = bfb(vv[l] - fromb(h));
      }
    }
  }
  {
    const float4* src = (const float4*)(M + (long long)tid * TT + P0);
    u16 hbuf[32], lbuf[32];
    #pragma unroll
    for (int q = 0; q < 8; ++q) {
      float4 v = src[q];
      float vv[4] = {v.x, v.y, v.z, v.w};
      #pragma unroll
      for (int l = 0; l < 4; ++l) {
        float x = -vv[l];
        u16 h = bfb(x);
        hbuf[q * 4 + l] = h;
        lbuf[q * 4 + l] = bfb(x - fromb(h));
      }
    }
    ushort4* dh = (ushort4*)(Ch + ((long long)b * TT + tid) * NB);
    ushort4* dl = (ushort4*)(Cl + ((long long)b * TT + tid) * NB);
    #pragma unroll
    for (int q = 0; q < 8; ++q) {
      ushort4 oh, ol;
      oh.x = hbuf[q*4+0]; oh.y = hbuf[q*4+1]; oh.z = hbuf[q*4+2]; oh.w = hbuf[q*4+3];
      ol.x = lbuf[q*4+0]; ol.y = lbuf[q*4+1]; ol.z = lbuf[q*4+2]; ol.w = lbuf[q*4+3];
      dh[q] = oh; dl[q] = ol;
    }
  }
  __syncthreads();

  if (wid == 0) {
    const int rl = lane & 31, h2 = lane >> 5;
    float d[16];
    #pragma unroll
    for (int j = 0; j < 16; ++j) {
      const int col = P0 + h2 * 16 + j;
      d[j] = fromb(RTh[col][rl]) + fromb(RTl[col][rl]);
    }
    gj32<ZLAST>(d, rl, h2);
    #pragma unroll
    for (int j = 0; j < 16; ++j) {
      u16 hh = bfb(d[j]);
      Dh[rl][h2 * 16 + j] = hh;
      Dl[rl][h2 * 16 + j] = bfb(d[j] - fromb(hh));
    }
  }
  __syncthreads();

  u16* Rbh = Rh + (long long)b * TT * NB;
  u16* Rbl = Rl + (long long)b * TT * NB;
  #pragma unroll
  for (int cf = 0; cf < 4; ++cf) {
    const int j = wid * 64 + cf * 16 + fr;
    const bf16x8 bh = *(const bf16x8*)&RTh[j][fq * 8];
    const bf16x8 bl = *(const bf16x8*)&RTl[j][fq * 8];
    const bool inP = ((unsigned)(j - P0)) < 32u;
    const int s = j - P0;
    #pragma unroll
    for (int fi = 0; fi < 2; ++fi) {
      const bf16x8 ah = *(const bf16x8*)&Dh[fi * 16 + fr][fq * 8];
      const bf16x8 al = *(const bf16x8*)&Dl[fi * 16 + fr][fq * 8];
      f32x4 acc = {};
      acc = __builtin_amdgcn_mfma_f32_16x16x32_bf16(ah, bh, acc, 0, 0, 0);
      acc = __builtin_amdgcn_mfma_f32_16x16x32_bf16(ah, bl, acc, 0, 0, 0);
      acc = __builtin_amdgcn_mfma_f32_16x16x32_bf16(al, bh, acc, 0, 0, 0);
      ushort4 oh, ol;
      u16* hp = (u16*)&oh; u16* lp = (u16*)&ol;
      float mvals[4];
      #pragma unroll
      for (int reg = 0; reg < 4; ++reg) {
        const int t = fi * 16 + fq * 4 + reg;
        float v = acc[reg];
        if (inP) v = fromb(Dh[t][s]) + fromb(Dl[t][s]);
        mvals[reg] = v;
        float rv = inP ? (v + ((t == s) ? 1.0f : 0.0f)) : v;
        u16 hh = bfb(rv);
        hp[reg] = hh;
        lp[reg] = bfb(rv - fromb(hh));
      }
      *(ushort4*)(Rbh + (long long)j * NB + fi * 16 + fq * 4) = oh;
      *(ushort4*)(Rbl + (long long)j * NB + fi * 16 + fq * 4) = ol;
      #pragma unroll
      for (int reg = 0; reg < 4; ++reg)
        M[(long long)(P0 + fi * 16 + fq * 4 + reg) * TT + j] = mvals[reg];
    }
  }
}

// Panel update (verified round 5)
__global__ __launch_bounds__(256) void panel_update(float* __restrict__ Mg,
    const u16* __restrict__ Ch, const u16* __restrict__ Cl,
    const u16* __restrict__ Rh, const u16* __restrict__ Rl, int p) {
  const int b = blockIdx.y;
  float* M = Mg + (long long)b * TT * TT;
  const u16* Cbh = Ch + (long long)b * TT * NB;
  const u16* Cbl = Cl + (long long)b * TT * NB;
  const u16* Rbh = Rh + (long long)b * TT * NB;
  const u16* Rbl = Rl + (long long)b * TT * NB;
  const int tid = threadIdx.x, wid = tid >> 6, lane = tid & 63;
  const int fr = lane & 15, fq = lane >> 4;
  const int r0 = blockIdx.x * 64 + wid * 16;
  const int P0 = p * NB;

  const bf16x8 ah = *(const bf16x8*)(Cbh + (long long)(r0 + fr) * NB + fq * 8);
  const bf16x8 al = *(const bf16x8*)(Cbl + (long long)(r0 + fr) * NB + fq * 8);

  f32x4 acc[16];
  #pragma unroll
  for (int cf = 0; cf < 16; ++cf) {
    const int j = cf * 16 + fr;
    const bf16x8 bh = *(const bf16x8*)(Rbh + (long long)j * NB + fq * 8);
    const bf16x8 bl = *(const bf16x8*)(Rbl + (long long)j * NB + fq * 8);
    f32x4 a = {};
    a = __builtin_amdgcn_mfma_f32_16x16x32_bf16(ah, bh, a, 0, 0, 0);
    a = __builtin_amdgcn_mfma_f32_16x16x32_bf16(ah, bl, a, 0, 0, 0);
    a = __builtin_amdgcn_mfma_f32_16x16x32_bf16(al, bh, a, 0, 0, 0);
    acc[cf] = a;
  }
  #pragma unroll
  for (int reg = 0; reg < 4; ++reg) {
    const int m = r0 + fq * 4 + reg;
    if ((unsigned)(m - P0) < 32u) continue;
    #pragma unroll
    for (int cf = 0; cf < 16; ++cf) {
      const int n = cf * 16 + fr;
      M[(long long)m * TT + n] += acc[cf][reg];
    }
  }
}

__global__ void out_kernel(const float* __restrict__ Aall, const float* __restrict__ Linv,
                           const float* __restrict__ f, float* __restrict__ out) {
  int bj = blockIdx.x;
  int b = bj >> 8, j = bj & 255;
  const float* Lrow = Linv + (long long)b * TT * TT + j * TT;
  const float* Ab   = Aall + (long long)b * TT * TT;
  float fbj = f[bj];
  float dg = Lrow[j];
  float l0 = Lrow[0];
  float* orow = out + (long long)bj * (TT + 1);
  for (int c = threadIdx.x; c < TT + 1; c += 256) {
    float v;
    if (c == 0) v = fbj * l0;
    else {
      int i = c - 1;
      float aij = Ab[i * TT + j];
      float t1 = (j > 0) ? dg : 0.f;
      float t2 = (i > 0) ? Lrow[i] : 0.f;
      v = aij * (t1 - t2);
    }
    orow[c] = v;
  }
}

extern "C" void kernel_launch(void* const* d_in, const int* in_sizes, int n_in,
                              void* d_out, int out_size, void* d_ws, size_t ws_size,
                              hipStream_t stream) {
  const float* inp = (const float*)d_in[0];
  const float* Wk  = (const float*)d_in[1];
  const float* bk  = (const float*)d_in[2];
  const float* Wq  = (const float*)d_in[3];
  const float* bq  = (const float*)d_in[4];
  const float* Wr  = (const float*)d_in[5];
  const float* br  = (const float*)d_in[6];
  float* out = (float*)d_out;

  // workspace layout (~112 MiB peak; 120.4 MiB proven available round 1)
  const long long NI = (long long)BB * TT * DD;   // 12,582,912
  u16* inpHi = (u16*)d_ws;
  u16* inpLo = inpHi + NI;
  u16* Zhi   = inpLo + NI;
  u16* Zlo   = Zhi + NI;
  u16* HTh   = Zlo + NI;
  u16* HTl   = HTh + (long long)DD * DD;
  u16* WqTh  = HTl + (long long)DD * DD;          // region later reused by A_
  u16* WqTl  = WqTh + (long long)DD * DD;
  u16* WkTh  = WqTl + (long long)DD * DD;
  u16* WkTl  = WkTh + (long long)DD * DD;
  float* A_  = (float*)WqTh;                      // aliases WqT/WkT (dead by einsum)
  float* f   = A_ + (long long)BB * TT * TT;
  float* cs  = f + BB * TT;
  float* us  = cs + BB * TT;
  float* vs_ = us + DD;
  float* spu = vs_ + DD;
  float* spv = spu + BB * TT;
  float* c0f = spv + BB * TT;
  // Z region reused after einsum:
  float* L   = (float*)Zhi;
  u16* Csth  = (u16*)(L + (long long)BB * TT * TT);
  u16* Cstl  = Csth + (long long)BB * TT * NB;
  u16* Rph   = Cstl + (long long)BB * TT * NB;
  u16* Rpl   = Rph  + (long long)BB * TT * NB;

  (void)hipFuncSetAttribute(reinterpret_cast<const void*>(&pg_kernel<0>),
                            hipFuncAttributeMaxDynamicSharedMemorySize, 65536);
  (void)hipFuncSetAttribute(reinterpret_cast<const void*>(&pg_kernel<1>),
                            hipFuncAttributeMaxDynamicSharedMemorySize, 65536);

  const float s = 0.03125f;
  const int M = BB * TT;  // 12288

  // 1. pre-split inp
  split_kernel<<<(int)(NI / 4 / 256), 256, 0, stream>>>(inp, inpHi, inpLo, (int)NI);

  // 2. WqT/WkT = transpose+split
  tsplit_kernel<<<dim3(32, 32, 2), dim3(32, 8), 0, stream>>>(Wq, Wk, WqTh, WqTl, WkTh, WkTl);

  // 3. bias helpers: c0 = s*bq.bk ; us = s*WqT.bk ; vs = s*WkT.bq
  c0_kernel<<<1, 256, 0, stream>>>(bq, bk, c0f);
  rootv_split_kernel<<<DD / 4, 256, 0, stream>>>(WqTh, WqTl, bk, us, s);
  rootv_split_kernel<<<DD / 4, 256, 0, stream>>>(WkTh, WkTl, bq, vs_, s);

  // 4. HT[e,d] = sum_n Wk[n,e]*Wq[n,d]  (bt-gemm(WkT, WqT), split out)
  pg_kernel<0><<<dim3(8, 8, 1), 256, 65536, stream>>>(
      WkTh, WkTl, WqTh, WqTl, HTh, HTl, nullptr, nullptr, nullptr,
      0.f, DD, DD, 0, 0, 0);

  // 5. Z = X @ H  (bt-gemm(inp, HT), split out)
  pg_kernel<0><<<dim3(M / 128, DD / 128, 1), 256, 65536, stream>>>(
      inpHi, inpLo, HTh, HTl, Zhi, Zlo, nullptr, nullptr, nullptr,
      0.f, DD, DD, 0, 0, 0);

  // 6. row/col biases: f = X.Wr + br ; spu = X.us + s*c0 ; spv = X.vs
  rootv_kernel<<<M / 4, 256, 0, stream>>>(inp, Wr, br, f);
  rootv_kernel<<<M / 4, 256, 0, stream>>>(inp, us, c0f, spu);
  rootv_kernel<<<M / 4, 256, 0, stream>>>(inp, vs_, nullptr, spv);

  // 7. A[b,t,s] = (t==s)?0:exp(s*(z_t.x_s) + spu[b,t] + spv[b,s])
  pg_kernel<1><<<dim3(TT / 128, TT / 128, BB), 256, 65536, stream>>>(
      Zhi, Zlo, inpHi, inpLo, nullptr, nullptr, A_, spu, spv,
      s, DD, TT, (long long)TT * DD, (long long)TT * DD, (long long)TT * TT);

  colsum_kernel<<<BB, TT, 0, stream>>>(A_, cs);
  buildL_kernel<<<BB * TT, TT, 0, stream>>>(A_, cs, f, L);

  // blocked Gauss-Jordan inverse: panels 1..7 then 0 (root row pivoted last)
  for (int pi = 0; pi < 8; ++pi) {
    const int p = (pi + 1) & 7;
    if (p == 0)
      panel_prep<true><<<BB, 256, 0, stream>>>(L, Csth, Cstl, Rph, Rpl, p);
    else
      panel_prep<false><<<BB, 256, 0, stream>>>(L, Csth, Cstl, Rph, Rpl, p);
    panel_update<<<dim3(4, BB), 256, 0, stream>>>(L, Csth, Cstl, Rph, Rpl, p);
  }

  out_kernel<<<BB * TT, TT, 0, stream>>>(A_, L, f, out);
}

// Round 8
// 418.359 us; speedup vs baseline: 55.6826x; 1.0224x over previous
//
#include <hip/hip_runtime.h>
#include <hip/hip_bf16.h>
#include <math.h>

#define BB 48
#define TT 256
#define DD 1024
#define NB 32

typedef __attribute__((ext_vector_type(8))) short bf16x8;
typedef __attribute__((ext_vector_type(4))) float f32x4;
typedef unsigned short u16;

__device__ __forceinline__ u16 bfb(float x) {
  __hip_bfloat16 h = __float2bfloat16(x);   // RNE
  return __builtin_bit_cast(u16, h);
}
__device__ __forceinline__ float fromb(u16 u) {
  unsigned v = (unsigned)u << 16;
  return __builtin_bit_cast(float, v);
}
__device__ __forceinline__ void gl16(const void* g, void* l) {
  __builtin_amdgcn_global_load_lds((const __attribute__((address_space(1))) unsigned int*)g,
                                   (__attribute__((address_space(3))) unsigned int*)l, 16, 0, 0);
}

// split x -> hi bf16 + lo bf16
__global__ void split_kernel(const float* __restrict__ src, u16* __restrict__ hi,
                             u16* __restrict__ lo, int n) {
  int idx = blockIdx.x * blockDim.x + threadIdx.x;
  if (idx * 4 >= n) return;
  float4 v = ((const float4*)src)[idx];
  ushort4 h, l;
  h.x = bfb(v.x); l.x = bfb(v.x - fromb(h.x));
  h.y = bfb(v.y); l.y = bfb(v.y - fromb(h.y));
  h.z = bfb(v.z); l.z = bfb(v.z - fromb(h.z));
  h.w = bfb(v.w); l.w = bfb(v.w - fromb(h.w));
  ((ushort4*)hi)[idx] = h;
  ((ushort4*)lo)[idx] = l;
}

// Transpose + split: WT[d][n] = split(W[n][d]). grid (32,32,2), block (32,8).
__global__ void tsplit_kernel(const float* __restrict__ Wq, const float* __restrict__ Wk,
                              u16* __restrict__ WqTh, u16* __restrict__ WqTl,
                              u16* __restrict__ WkTh, u16* __restrict__ WkTl) {
  const float* W = blockIdx.z ? Wk : Wq;
  u16* Th = blockIdx.z ? WkTh : WqTh;
  u16* Tl = blockIdx.z ? WkTl : WqTl;
  __shared__ float t[32][33];
  const int tx = threadIdx.x, ty = threadIdx.y;
  const int x = blockIdx.x * 32 + tx;
  #pragma unroll
  for (int j = 0; j < 32; j += 8)
    t[ty + j][tx] = W[(long long)(blockIdx.y * 32 + ty + j) * DD + x];
  __syncthreads();
  const int n = blockIdx.y * 32 + tx;
  #pragma unroll
  for (int j = 0; j < 32; j += 8) {
    const int d = blockIdx.x * 32 + ty + j;
    float v = t[tx][ty + j];
    u16 h = bfb(v);
    Th[(long long)d * DD + n] = h;
    Tl[(long long)d * DD + n] = bfb(v - fromb(h));
  }
}

// c0f[0] = s * dot(bq, bk)
__global__ void c0_kernel(const float* __restrict__ bq, const float* __restrict__ bk,
                          float* __restrict__ c0f) {
  __shared__ float ws4[4];
  const int tid = threadIdx.x, lane = tid & 63, wave = tid >> 6;
  float s = 0.f;
  #pragma unroll
  for (int q = 0; q < 4; ++q) { int d = tid + q * 256; s += bq[d] * bk[d]; }
  #pragma unroll
  for (int off = 32; off; off >>= 1) s += __shfl_down(s, off);
  if (lane == 0) ws4[wave] = s;
  __syncthreads();
  if (tid == 0) c0f[0] = 0.03125f * (ws4[0] + ws4[1] + ws4[2] + ws4[3]);
}

// out[row] = scale * dot(hi[row]+lo[row], w)
__global__ void rootv_split_kernel(const u16* __restrict__ Th, const u16* __restrict__ Tl,
                                   const float* __restrict__ w, float* __restrict__ out,
                                   float scale) {
  const int wave = threadIdx.x >> 6, lane = threadIdx.x & 63;
  const int row = blockIdx.x * 4 + wave;
  const u16* th = Th + (long long)row * DD;
  const u16* tl = Tl + (long long)row * DD;
  float s = 0.f;
  #pragma unroll
  for (int q = 0; q < DD / 64; ++q) {
    int d = lane + q * 64;
    s += (fromb(th[d]) + fromb(tl[d])) * w[d];
  }
  #pragma unroll
  for (int off = 32; off; off >>= 1) s += __shfl_down(s, off);
  if (lane == 0) out[row] = scale * s;
}

// Fused triple row-dot: f = X.Wr + br ; spu = X.us + c0 ; spv = X.vs  (inp read once)
__global__ void rootv3_kernel(const float* __restrict__ X, const float* __restrict__ Wr,
                              const float* __restrict__ br, const float* __restrict__ us,
                              const float* __restrict__ vs, const float* __restrict__ c0f,
                              float* __restrict__ f, float* __restrict__ spu,
                              float* __restrict__ spv) {
  const int wave = threadIdx.x >> 6, lane = threadIdx.x & 63;
  const int row = blockIdx.x * 4 + wave;
  const float* r = X + (long long)row * DD;
  float s1 = 0.f, s2 = 0.f, s3 = 0.f;
  #pragma unroll
  for (int q = 0; q < DD / 64; ++q) {
    const int d = lane + q * 64;
    const float x = r[d];
    s1 = fmaf(x, Wr[d], s1);
    s2 = fmaf(x, us[d], s2);
    s3 = fmaf(x, vs[d], s3);
  }
  #pragma unroll
  for (int off = 32; off; off >>= 1) {
    s1 += __shfl_down(s1, off);
    s2 += __shfl_down(s2, off);
    s3 += __shfl_down(s3, off);
  }
  if (lane == 0) {
    f[row]   = s1 + br[0];
    spu[row] = s2 + c0f[0];
    spv[row] = s3;
  }
}

// Pre-split GEMM: C[m,n] = sum_k (Ah+Al)[m,k]*(Bh+Bl)[n,k], 3-term split-bf16 MFMA.
// lda = element row stride (decoupled from K-extent Kd, enabling split-K).
// EPI 0: Ch/Cl = split(acc) ; EPI 1: Cf = exp(s*acc+spu[m]+spv[n]), zero diag ;
// EPI 2: Cf = acc (f32 partial, for split-K).
template<int EPI>
__global__ __launch_bounds__(256) void pg_kernel(
    const u16* __restrict__ Ah, const u16* __restrict__ Al,
    const u16* __restrict__ Bh, const u16* __restrict__ Bl,
    u16* __restrict__ Ch, u16* __restrict__ Cl, float* __restrict__ Cf,
    const float* __restrict__ spu, const float* __restrict__ spv,
    float sscale, int Kd, int Nsz, int lda,
    long long sA, long long sB, long long sC) {
  extern __shared__ char lds[];   // 2 x {Ahi,Alo,Bhi,Blo} x 8KB = 64 KB
  // XCD-aware bijective swizzle over (x,y) when wg count divisible by 8 [T1]
  int bx = blockIdx.x, by = blockIdx.y;
  {
    const int nw = gridDim.x * gridDim.y;
    if ((nw & 7) == 0) {
      int lin = by * gridDim.x + bx;
      const int cpx = nw >> 3;
      lin = (lin & 7) * cpx + (lin >> 3);
      bx = lin % gridDim.x; by = lin / gridDim.x;
    }
  }
  const int tid = threadIdx.x;
  const int m0 = bx * 128, n0 = by * 128;
  const int z = blockIdx.z;
  const u16* Abh = Ah + (long long)z * sA;
  const u16* Abl = Al + (long long)z * sA;
  const u16* Bbh = Bh + (long long)z * sB;
  const u16* Bbl = Bl + (long long)z * sB;

  const int srow = tid >> 2;            // 0..63
  const int scol = (tid & 3) * 8;       // u16 offset (16B chunk)
  const u16* a0 = Abh + (long long)(m0 + srow) * lda + scol;
  const u16* a1 = Abl + (long long)(m0 + srow) * lda + scol;
  const u16* b0 = Bbh + (long long)(n0 + srow) * lda + scol;
  const u16* b1 = Bbl + (long long)(n0 + srow) * lda + scol;
  const long long half = (long long)64 * lda;

  const int lane = tid & 63, wid = tid >> 6;
  const int wr = wid >> 1, wc = wid & 1;
  const int fr = lane & 15, fq = lane >> 4;

  f32x4 acc[4][4] = {};

  { // prologue: stage step 0 into buffer 0
    char* d = lds + tid * 16;
    gl16(a0, d);          gl16(a0 + half, d + 4096);
    gl16(a1, d + 8192);   gl16(a1 + half, d + 12288);
    gl16(b0, d + 16384);  gl16(b0 + half, d + 20480);
    gl16(b1, d + 24576);  gl16(b1 + half, d + 28672);
  }

  const int NS = Kd / 32;
  for (int s = 0; s < NS; ++s) {
    const int bb = (s & 1) << 15;
    __syncthreads();    // buf[s&1] landed; all waves' prior ds_reads drained

    if (s + 1 < NS) {   // stage next step into the other buffer (flies under MFMA)
      const int ko = (s + 1) * 32;
      char* d = lds + (((s + 1) & 1) << 15) + tid * 16;
      gl16(a0 + ko, d);          gl16(a0 + ko + half, d + 4096);
      gl16(a1 + ko, d + 8192);   gl16(a1 + ko + half, d + 12288);
      gl16(b0 + ko, d + 16384);  gl16(b0 + ko + half, d + 20480);
      gl16(b1 + ko, d + 24576);  gl16(b1 + ko + half, d + 28672);
    }

    const char* Ahs = lds + bb;
    const char* Als = lds + bb + 8192;
    const char* Bhs = lds + bb + 16384;
    const char* Bls = lds + bb + 24576;
    bf16x8 fah[4], fal[4], fbh[4], fbl[4];
    #pragma unroll
    for (int im = 0; im < 4; ++im) {
      const int off = (wr * 64 + im * 16 + fr) * 64 + fq * 16;
      fah[im] = *(const bf16x8*)(Ahs + off);
      fal[im] = *(const bf16x8*)(Als + off);
    }
    #pragma unroll
    for (int jn = 0; jn < 4; ++jn) {
      const int off = (wc * 64 + jn * 16 + fr) * 64 + fq * 16;
      fbh[jn] = *(const bf16x8*)(Bhs + off);
      fbl[jn] = *(const bf16x8*)(Bls + off);
    }
    #pragma unroll
    for (int im = 0; im < 4; ++im)
      #pragma unroll
      for (int jn = 0; jn < 4; ++jn) {
        acc[im][jn] = __builtin_amdgcn_mfma_f32_16x16x32_bf16(fah[im], fbh[jn], acc[im][jn], 0, 0, 0);
        acc[im][jn] = __builtin_amdgcn_mfma_f32_16x16x32_bf16(fah[im], fbl[jn], acc[im][jn], 0, 0, 0);
        acc[im][jn] = __builtin_amdgcn_mfma_f32_16x16x32_bf16(fal[im], fbh[jn], acc[im][jn], 0, 0, 0);
      }
  }

  // epilogue: C/D layout col=lane&15, row=(lane>>4)*4+reg  [verified rounds 3-6]
  #pragma unroll
  for (int im = 0; im < 4; ++im) {
    #pragma unroll
    for (int jn = 0; jn < 4; ++jn) {
      const int mbase = m0 + wr * 64 + im * 16 + fq * 4;
      const int n     = n0 + wc * 64 + jn * 16 + fr;
      #pragma unroll
      for (int reg = 0; reg < 4; ++reg) {
        const int m = mbase + reg;
        const float v = acc[im][jn][reg];
        if (EPI == 0) {
          u16 h = bfb(v);
          Ch[(long long)z * sC + (long long)m * Nsz + n] = h;
          Cl[(long long)z * sC + (long long)m * Nsz + n] = bfb(v - fromb(h));
        } else if (EPI == 1) {
          float e = expf(fmaf(sscale, v, spu[z * TT + m] + spv[z * TT + n]));
          if (m == n) e = 0.f;
          Cf[(long long)z * sC + (long long)m * Nsz + n] = e;
        } else {
          Cf[(long long)z * sC + (long long)m * Nsz + n] = v;
        }
      }
    }
  }
}

// sum 4 split-K partials -> split bf16 hi/lo
__global__ void combine_ht(const float* __restrict__ part, u16* __restrict__ hi,
                           u16* __restrict__ lo) {
  const long long idx = (long long)blockIdx.x * 256 + threadIdx.x;  // float4 units
  const long long NQ = (long long)DD * DD / 4;
  const float4* p = (const float4*)part;
  float4 a = p[idx], b = p[idx + NQ], c = p[idx + 2 * NQ], d = p[idx + 3 * NQ];
  float vv[4] = {a.x + b.x + c.x + d.x, a.y + b.y + c.y + d.y,
                 a.z + b.z + c.z + d.z, a.w + b.w + c.w + d.w};
  ushort4 h, l;
  u16* hp = (u16*)&h; u16* lp = (u16*)&l;
  #pragma unroll
  for (int e = 0; e < 4; ++e) {
    u16 hh = bfb(vv[e]);
    hp[e] = hh; lp[e] = bfb(vv[e] - fromb(hh));
  }
  ((ushort4*)hi)[idx] = h;
  ((ushort4*)lo)[idx] = l;
}

// Fused colsum + Laplacian build: L[b,0,j]=f[b,j]; L[b,i,j]=-A+(i==j)*colsum
__global__ void csbl_kernel(const float* __restrict__ Aall, const float* __restrict__ f,
                            float* __restrict__ L) {
  const int b = blockIdx.x, j = threadIdx.x;
  const float* Ab = Aall + (long long)b * TT * TT;
  float* Lb = L + (long long)b * TT * TT;
  float s = 0.f;
  for (int i = 0; i < TT; ++i) s += Ab[i * TT + j];
  Lb[j] = f[b * TT + j];
  for (int i = 1; i < TT; ++i) {
    float v = -Ab[i * TT + j];
    if (i == j) v += s;
    Lb[i * TT + j] = v;
  }
}

// 32x32 Gauss-Jordan inverse in one wave's registers (verified round 4).
template<bool ZLAST>
__device__ __forceinline__ void gj32(float* d, int rl, int h) {
  #pragma unroll
  for (int s = 0; s < 32; ++s) {
    const int t = ZLAST ? ((s + 1) & 31) : s;
    const int tl = t & 15, th = t >> 4;
    float rowv[16];
    #pragma unroll
    for (int j = 0; j < 16; ++j) rowv[j] = __shfl(d[j], t + 32 * h);
    const float pv   = __shfl(d[tl], t + 32 * th);
    const float colv = __shfl(d[tl], rl + 32 * th);
    const float ip = 1.0f / pv;
    if (rl == t) {
      #pragma unroll
      for (int j = 0; j < 16; ++j) {
        float v = rowv[j] * ip;
        if (j == tl) v = (h == th) ? ip : v;
        d[j] = v;
      }
    } else {
      const float cip = colv * ip;
      #pragma unroll
      for (int j = 0; j < 16; ++j) {
        float v = fmaf(-cip, rowv[j], d[j]);
        if (j == tl) v = (h == th) ? -cip : v;
        d[j] = v;
      }
    }
  }
}

// Single-block-per-matrix blocked Gauss-Jordan: 48 blocks x 256 threads, matrix
// in global (L2-resident), ALL staging in 85 KB dynamic LDS, only __syncthreads.
// Per panel p (order 1..7 then 0):
//  1. stage R^T split (RT) + split(-C) (Cb) in LDS
//  2. wave 0: Dinv via register/shfl gj32 -> Dh/Dl
//  3. Rp = Dinv @ R via MFMA, IN-PLACE into RT (each wave owns its 64 columns ->
//     race-free); write M pivot rows (pivot block = exact Dinv)
//  4. rank-32 update: 4 chunks x (48 MFMA/wave) + direct global RMW on M,
//     pivot rows skipped (written in step 3)
// LDS byte offsets:
#define G1_RTH 0        // u16 [256][40]
#define G1_RTL 20480
#define G1_CH  40960    // u16 [256][40]
#define G1_CL  61440
#define G1_DH  81920    // u16 [32][40]
#define G1_DL  84480
#define G1_LDS 87040
__global__ __launch_bounds__(256) void gj_single(float* __restrict__ Mg) {
  extern __shared__ char lds[];
  u16* RTh = (u16*)(lds + G1_RTH);
  u16* RTl = (u16*)(lds + G1_RTL);
  u16* Cbh = (u16*)(lds + G1_CH);
  u16* Cbl = (u16*)(lds + G1_CL);
  u16* Dh  = (u16*)(lds + G1_DH);
  u16* Dl  = (u16*)(lds + G1_DL);
  float* M = Mg + (long long)blockIdx.x * TT * TT;
  const int tid = threadIdx.x, wid = tid >> 6, lane = tid & 63;
  const int fr = lane & 15, fq = lane >> 4;

  for (int pi = 0; pi < 8; ++pi) {
    const int p = (pi + 1) & 7;
    const int P0 = p * NB;

    // ---- step 1a: stage R^T split. thread: R row sr=tid>>3, 32 cols from (tid&7)*32
    {
      const int sr = tid >> 3, sc0 = (tid & 7) * 32;
      const float4* src = (const float4*)(M + (long long)(P0 + sr) * TT + sc0);
      #pragma unroll
      for (int q = 0; q < 8; ++q) {
        float4 v = src[q];
        float vv[4] = {v.x, v.y, v.z, v.w};
        #pragma unroll
        for (int l = 0; l < 4; ++l) {
          const int j = sc0 + q * 4 + l;
          u16 h = bfb(vv[l]);
          RTh[j * 40 + sr] = h;
          RTl[j * 40 + sr] = bfb(vv[l] - fromb(h));
        }
      }
    }
    // ---- step 1b: split(-C): row tid, cols P0..P0+31
    {
      const float4* src = (const float4*)(M + (long long)tid * TT + P0);
      #pragma unroll
      for (int q = 0; q < 8; ++q) {
        float4 v = src[q];
        float vv[4] = {v.x, v.y, v.z, v.w};
        #pragma unroll
        for (int l = 0; l < 4; ++l) {
          const int t = q * 4 + l;
          float x = -vv[l];
          u16 h = bfb(x);
          Cbh[tid * 40 + t] = h;
          Cbl[tid * 40 + t] = bfb(x - fromb(h));
        }
      }
    }
    __syncthreads();

    // ---- step 2: wave 0 computes Dinv
    if (wid == 0) {
      const int rl = lane & 31, h2 = lane >> 5;
      float d[16];
      #pragma unroll
      for (int j = 0; j < 16; ++j) {
        const int col = P0 + h2 * 16 + j;
        d[j] = fromb(RTh[col * 40 + rl]) + fromb(RTl[col * 40 + rl]);
      }
      if (p == 0) gj32<true>(d, rl, h2); else gj32<false>(d, rl, h2);
      #pragma unroll
      for (int j = 0; j < 16; ++j) {
        u16 hh = bfb(d[j]);
        Dh[rl * 40 + h2 * 16 + j] = hh;
        Dl[rl * 40 + h2 * 16 + j] = bfb(d[j] - fromb(hh));
      }
    }
    __syncthreads();

    // ---- step 3: Rp = Dinv @ R, in-place into RT; write M pivot rows.
    // Wave reads/writes ONLY its own 64 columns (j = wid*64+...) -> no race.
    #pragma unroll
    for (int cf = 0; cf < 4; ++cf) {
      const int j = wid * 64 + cf * 16 + fr;
      const bf16x8 bh = *(const bf16x8*)&RTh[j * 40 + fq * 8];
      const bf16x8 bl = *(const bf16x8*)&RTl[j * 40 + fq * 8];
      const bool inP = ((unsigned)(j - P0)) < 32u;
      const int s = j - P0;
      f32x4 acc2[2];
      #pragma unroll
      for (int fi = 0; fi < 2; ++fi) {
        const bf16x8 ah = *(const bf16x8*)&Dh[(fi * 16 + fr) * 40 + fq * 8];
        const bf16x8 al = *(const bf16x8*)&Dl[(fi * 16 + fr) * 40 + fq * 8];
        f32x4 a = {};
        a = __builtin_amdgcn_mfma_f32_16x16x32_bf16(ah, bh, a, 0, 0, 0);
        a = __builtin_amdgcn_mfma_f32_16x16x32_bf16(ah, bl, a, 0, 0, 0);
        a = __builtin_amdgcn_mfma_f32_16x16x32_bf16(al, bh, a, 0, 0, 0);
        acc2[fi] = a;
      }
      #pragma unroll
      for (int fi = 0; fi < 2; ++fi) {
        ushort4 oh, ol;
        u16* hp = (u16*)&oh; u16* lp = (u16*)&ol;
        float mvals[4];
        #pragma unroll
        for (int reg = 0; reg < 4; ++reg) {
          const int t = fi * 16 + fq * 4 + reg;
          float v = acc2[fi][reg];
          if (inP) v = fromb(Dh[t * 40 + s]) + fromb(Dl[t * 40 + s]);  // exact Dinv
          mvals[reg] = v;
          float rv = inP ? (v + ((t == s) ? 1.0f : 0.0f)) : v;  // staging: Dinv+I
          u16 hh = bfb(rv);
          hp[reg] = hh;
          lp[reg] = bfb(rv - fromb(hh));
        }
        *(ushort4*)&RTh[j * 40 + fi * 16 + fq * 4] = oh;
        *(ushort4*)&RTl[j * 40 + fi * 16 + fq * 4] = ol;
        #pragma unroll
        for (int reg = 0; reg < 4; ++reg)
          M[(long long)(P0 + fi * 16 + fq * 4 + reg) * TT + j] = mvals[reg];
      }
    }
    __syncthreads();   // RT now holds RpB^T for ALL columns; update reads all

    // ---- step 4: rank-32 update, 4 chunks of 64 rows (wave: 16 rows/chunk)
    #pragma unroll 1
    for (int ch = 0; ch < 4; ++ch) {
      const int r0 = ch * 64 + wid * 16;
      const bf16x8 ah = *(const bf16x8*)&Cbh[(r0 + fr) * 40 + fq * 8];
      const bf16x8 al = *(const bf16x8*)&Cbl[(r0 + fr) * 40 + fq * 8];
      f32x4 acc[16];
      #pragma unroll
      for (int cf = 0; cf < 16; ++cf) {
        const int j = cf * 16 + fr;
        const bf16x8 bh = *(const bf16x8*)&RTh[j * 40 + fq * 8];
        const bf16x8 bl = *(const bf16x8*)&RTl[j * 40 + fq * 8];
        f32x4 a = {};
        a = __builtin_amdgcn_mfma_f32_16x16x32_bf16(ah, bh, a, 0, 0, 0);
        a = __builtin_amdgcn_mfma_f32_16x16x32_bf16(ah, bl, a, 0, 0, 0);
        a = __builtin_amdgcn_mfma_f32_16x16x32_bf16(al, bh, a, 0, 0, 0);
        acc[cf] = a;
      }
      #pragma unroll
      for (int reg = 0; reg < 4; ++reg) {
        const int m = r0 + fq * 4 + reg;
        if ((unsigned)(m - P0) < 32u) continue;   // pivot rows done in step 3
        #pragma unroll
        for (int cf = 0; cf < 16; ++cf) {
          const int n = cf * 16 + fr;
          M[(long long)m * TT + n] += acc[cf][reg];
        }
      }
    }
    __syncthreads();   // M updated + staging free before next panel
  }
}

__global__ void out_kernel(const float* __restrict__ Aall, const float* __restrict__ Linv,
                           const float* __restrict__ f, float* __restrict__ out) {
  int bj = blockIdx.x;
  int b = bj >> 8, j = bj & 255;
  const float* Lrow = Linv + (long long)b * TT * TT + j * TT;
  const float* Ab   = Aall + (long long)b * TT * TT;
  float fbj = f[bj];
  float dg = Lrow[j];
  float l0 = Lrow[0];
  float* orow = out + (long long)bj * (TT + 1);
  for (int c = threadIdx.x; c < TT + 1; c += 256) {
    float v;
    if (c == 0) v = fbj * l0;
    else {
      int i = c - 1;
      float aij = Ab[i * TT + j];
      float t1 = (j > 0) ? dg : 0.f;
      float t2 = (i > 0) ? Lrow[i] : 0.f;
      v = aij * (t1 - t2);
    }
    orow[c] = v;
  }
}

extern "C" void kernel_launch(void* const* d_in, const int* in_sizes, int n_in,
                              void* d_out, int out_size, void* d_ws, size_t ws_size,
                              hipStream_t stream) {
  const float* inp = (const float*)d_in[0];
  const float* Wk  = (const float*)d_in[1];
  const float* bk  = (const float*)d_in[2];
  const float* Wq  = (const float*)d_in[3];
  const float* bq  = (const float*)d_in[4];
  const float* Wr  = (const float*)d_in[5];
  const float* br  = (const float*)d_in[6];
  float* out = (float*)d_out;

  // workspace layout (~117.5 MiB peak; 126 MiB proven available round 1)
  const long long NI = (long long)BB * TT * DD;   // 12,582,912
  u16* inpHi = (u16*)d_ws;
  u16* inpLo = inpHi + NI;
  u16* Zhi   = inpLo + NI;
  u16* Zlo   = Zhi + NI;
  u16* HTh   = Zlo + NI;
  u16* HTl   = HTh + (long long)DD * DD;
  u16* WqTh  = HTl + (long long)DD * DD;          // region later reused by A_
  u16* WqTl  = WqTh + (long long)DD * DD;
  u16* WkTh  = WqTl + (long long)DD * DD;
  u16* WkTl  = WkTh + (long long)DD * DD;
  float* A_  = (float*)WqTh;                      // aliases WqT/WkT (dead by einsum)
  float* f   = A_ + (long long)BB * TT * TT;
  float* cs  = f + BB * TT;                       // (unused slot kept for layout)
  float* us  = cs + BB * TT;
  float* vs_ = us + DD;
  float* spu = vs_ + DD;
  float* spv = spu + BB * TT;
  float* c0f = spv + BB * TT;
  // Z region reused: HT split-K partials (before Z), then L (after einsum)
  float* HTpart = (float*)Zhi;                    // 4 x DD x DD f32 = 16 MB
  float* L   = (float*)Zhi;

  (void)hipFuncSetAttribute(reinterpret_cast<const void*>(&pg_kernel<0>),
                            hipFuncAttributeMaxDynamicSharedMemorySize, 65536);
  (void)hipFuncSetAttribute(reinterpret_cast<const void*>(&pg_kernel<1>),
                            hipFuncAttributeMaxDynamicSharedMemorySize, 65536);
  (void)hipFuncSetAttribute(reinterpret_cast<const void*>(&pg_kernel<2>),
                            hipFuncAttributeMaxDynamicSharedMemorySize, 65536);
  (void)hipFuncSetAttribute(reinterpret_cast<const void*>(&gj_single),
                            hipFuncAttributeMaxDynamicSharedMemorySize, G1_LDS);

  const float s = 0.03125f;
  const int M = BB * TT;  // 12288

  // 1. pre-split inp
  split_kernel<<<(int)(NI / 4 / 256), 256, 0, stream>>>(inp, inpHi, inpLo, (int)NI);

  // 2. WqT/WkT = transpose+split
  tsplit_kernel<<<dim3(32, 32, 2), dim3(32, 8), 0, stream>>>(Wq, Wk, WqTh, WqTl, WkTh, WkTl);

  // 3. bias helpers: c0 = s*bq.bk ; us = s*WqT.bk ; vs = s*WkT.bq
  c0_kernel<<<1, 256, 0, stream>>>(bq, bk, c0f);
  rootv_split_kernel<<<DD / 4, 256, 0, stream>>>(WqTh, WqTl, bk, us, s);
  rootv_split_kernel<<<DD / 4, 256, 0, stream>>>(WkTh, WkTl, bq, vs_, s);

  // 4. HT[e,d] = sum_n Wk[n,e]*Wq[n,d] via split-K (4 partials) + combine
  pg_kernel<2><<<dim3(8, 8, 4), 256, 65536, stream>>>(
      WkTh, WkTl, WqTh, WqTl, nullptr, nullptr, HTpart, nullptr, nullptr,
      0.f, 256, DD, DD, 256, 256, (long long)DD * DD);
  combine_ht<<<DD * DD / 4 / 256, 256, 0, stream>>>(HTpart, HTh, HTl);

  // 5. Z = X @ H  (overwrites HTpart region — stream-ordered after combine)
  pg_kernel<0><<<dim3(M / 128, DD / 128, 1), 256, 65536, stream>>>(
      inpHi, inpLo, HTh, HTl, Zhi, Zlo, nullptr, nullptr, nullptr,
      0.f, DD, DD, DD, 0, 0, 0);

  // 6. fused row dots: f = X.Wr+br ; spu = X.us+c0 ; spv = X.vs
  rootv3_kernel<<<M / 4, 256, 0, stream>>>(inp, Wr, br, us, vs_, c0f, f, spu, spv);

  // 7. A[b,t,s] = (t==s)?0:exp(s*(z_t.x_s) + spu[b,t] + spv[b,s])
  pg_kernel<1><<<dim3(TT / 128, TT / 128, BB), 256, 65536, stream>>>(
      Zhi, Zlo, inpHi, inpLo, nullptr, nullptr, A_, spu, spv,
      s, DD, TT, DD, (long long)TT * DD, (long long)TT * DD, (long long)TT * TT);

  // 8. fused colsum + Laplacian build (L aliases Zhi; Z dead after einsum)
  csbl_kernel<<<BB, TT, 0, stream>>>(A_, f, L);

  // 9. single-kernel blocked Gauss-Jordan inverse (panels 1..7 then 0)
  gj_single<<<BB, 256, G1_LDS, stream>>>(L);

  out_kernel<<<BB * TT, TT, 0, stream>>>(A_, L, f, out);
}

// Round 9
// 344.994 us; speedup vs baseline: 67.5237x; 1.2127x over previous
//
#include <hip/hip_runtime.h>
#include <hip/hip_bf16.h>
#include <math.h>

#define BB 48
#define TT 256
#define DD 1024
#define NB 32

typedef __attribute__((ext_vector_type(8))) short bf16x8;
typedef __attribute__((ext_vector_type(4))) float f32x4;
typedef unsigned short u16;

__device__ __forceinline__ u16 bfb(float x) {
  __hip_bfloat16 h = __float2bfloat16(x);   // RNE
  return __builtin_bit_cast(u16, h);
}
__device__ __forceinline__ float fromb(u16 u) {
  unsigned v = (unsigned)u << 16;
  return __builtin_bit_cast(float, v);
}
__device__ __forceinline__ void gl16(const void* g, void* l) {
  __builtin_amdgcn_global_load_lds((const __attribute__((address_space(1))) unsigned int*)g,
                                   (__attribute__((address_space(3))) unsigned int*)l, 16, 0, 0);
}

// split x -> hi bf16 + lo bf16
__global__ void split_kernel(const float* __restrict__ src, u16* __restrict__ hi,
                             u16* __restrict__ lo, int n) {
  int idx = blockIdx.x * blockDim.x + threadIdx.x;
  if (idx * 4 >= n) return;
  float4 v = ((const float4*)src)[idx];
  ushort4 h, l;
  h.x = bfb(v.x); l.x = bfb(v.x - fromb(h.x));
  h.y = bfb(v.y); l.y = bfb(v.y - fromb(h.y));
  h.z = bfb(v.z); l.z = bfb(v.z - fromb(h.z));
  h.w = bfb(v.w); l.w = bfb(v.w - fromb(h.w));
  ((ushort4*)hi)[idx] = h;
  ((ushort4*)lo)[idx] = l;
}

// Transpose + split: WT[d][n] = split(W[n][d]). grid (32,32,2), block (32,8).
__global__ void tsplit_kernel(const float* __restrict__ Wq, const float* __restrict__ Wk,
                              u16* __restrict__ WqTh, u16* __restrict__ WqTl,
                              u16* __restrict__ WkTh, u16* __restrict__ WkTl) {
  const float* W = blockIdx.z ? Wk : Wq;
  u16* Th = blockIdx.z ? WkTh : WqTh;
  u16* Tl = blockIdx.z ? WkTl : WqTl;
  __shared__ float t[32][33];
  const int tx = threadIdx.x, ty = threadIdx.y;
  const int x = blockIdx.x * 32 + tx;
  #pragma unroll
  for (int j = 0; j < 32; j += 8)
    t[ty + j][tx] = W[(long long)(blockIdx.y * 32 + ty + j) * DD + x];
  __syncthreads();
  const int n = blockIdx.y * 32 + tx;
  #pragma unroll
  for (int j = 0; j < 32; j += 8) {
    const int d = blockIdx.x * 32 + ty + j;
    float v = t[tx][ty + j];
    u16 h = bfb(v);
    Th[(long long)d * DD + n] = h;
    Tl[(long long)d * DD + n] = bfb(v - fromb(h));
  }
}

// c0f[0] = s * dot(bq, bk)
__global__ void c0_kernel(const float* __restrict__ bq, const float* __restrict__ bk,
                          float* __restrict__ c0f) {
  __shared__ float ws4[4];
  const int tid = threadIdx.x, lane = tid & 63, wave = tid >> 6;
  float s = 0.f;
  #pragma unroll
  for (int q = 0; q < 4; ++q) { int d = tid + q * 256; s += bq[d] * bk[d]; }
  #pragma unroll
  for (int off = 32; off; off >>= 1) s += __shfl_down(s, off);
  if (lane == 0) ws4[wave] = s;
  __syncthreads();
  if (tid == 0) c0f[0] = 0.03125f * (ws4[0] + ws4[1] + ws4[2] + ws4[3]);
}

// out[row] = scale * dot(hi[row]+lo[row], w)
__global__ void rootv_split_kernel(const u16* __restrict__ Th, const u16* __restrict__ Tl,
                                   const float* __restrict__ w, float* __restrict__ out,
                                   float scale) {
  const int wave = threadIdx.x >> 6, lane = threadIdx.x & 63;
  const int row = blockIdx.x * 4 + wave;
  const u16* th = Th + (long long)row * DD;
  const u16* tl = Tl + (long long)row * DD;
  float s = 0.f;
  #pragma unroll
  for (int q = 0; q < DD / 64; ++q) {
    int d = lane + q * 64;
    s += (fromb(th[d]) + fromb(tl[d])) * w[d];
  }
  #pragma unroll
  for (int off = 32; off; off >>= 1) s += __shfl_down(s, off);
  if (lane == 0) out[row] = scale * s;
}

// Fused triple row-dot: f = X.Wr + br ; spu = X.us + c0 ; spv = X.vs  (inp read once)
__global__ void rootv3_kernel(const float* __restrict__ X, const float* __restrict__ Wr,
                              const float* __restrict__ br, const float* __restrict__ us,
                              const float* __restrict__ vs, const float* __restrict__ c0f,
                              float* __restrict__ f, float* __restrict__ spu,
                              float* __restrict__ spv) {
  const int wave = threadIdx.x >> 6, lane = threadIdx.x & 63;
  const int row = blockIdx.x * 4 + wave;
  const float* r = X + (long long)row * DD;
  float s1 = 0.f, s2 = 0.f, s3 = 0.f;
  #pragma unroll
  for (int q = 0; q < DD / 64; ++q) {
    const int d = lane + q * 64;
    const float x = r[d];
    s1 = fmaf(x, Wr[d], s1);
    s2 = fmaf(x, us[d], s2);
    s3 = fmaf(x, vs[d], s3);
  }
  #pragma unroll
  for (int off = 32; off; off >>= 1) {
    s1 += __shfl_down(s1, off);
    s2 += __shfl_down(s2, off);
    s3 += __shfl_down(s3, off);
  }
  if (lane == 0) {
    f[row]   = s1 + br[0];
    spu[row] = s2 + c0f[0];
    spv[row] = s3;
  }
}

// Pre-split GEMM: C[m,n] = sum_k (Ah+Al)[m,k]*(Bh+Bl)[n,k], 3-term split-bf16 MFMA.
// lda = element row stride (decoupled from K-extent Kd, enabling split-K).
// EPI 0: Ch/Cl = split(acc) ; EPI 1: Cf = exp(s*acc+spu[m]+spv[n]), zero diag ;
// EPI 2: Cf = acc (f32 partial, for split-K).
template<int EPI>
__global__ __launch_bounds__(256) void pg_kernel(
    const u16* __restrict__ Ah, const u16* __restrict__ Al,
    const u16* __restrict__ Bh, const u16* __restrict__ Bl,
    u16* __restrict__ Ch, u16* __restrict__ Cl, float* __restrict__ Cf,
    const float* __restrict__ spu, const float* __restrict__ spv,
    float sscale, int Kd, int Nsz, int lda,
    long long sA, long long sB, long long sC) {
  extern __shared__ char lds[];   // 2 x {Ahi,Alo,Bhi,Blo} x 8KB = 64 KB
  // XCD-aware bijective swizzle over (x,y) when wg count divisible by 8 [T1]
  int bx = blockIdx.x, by = blockIdx.y;
  {
    const int nw = gridDim.x * gridDim.y;
    if ((nw & 7) == 0) {
      int lin = by * gridDim.x + bx;
      const int cpx = nw >> 3;
      lin = (lin & 7) * cpx + (lin >> 3);
      bx = lin % gridDim.x; by = lin / gridDim.x;
    }
  }
  const int tid = threadIdx.x;
  const int m0 = bx * 128, n0 = by * 128;
  const int z = blockIdx.z;
  const u16* Abh = Ah + (long long)z * sA;
  const u16* Abl = Al + (long long)z * sA;
  const u16* Bbh = Bh + (long long)z * sB;
  const u16* Bbl = Bl + (long long)z * sB;

  const int srow = tid >> 2;            // 0..63
  const int scol = (tid & 3) * 8;       // u16 offset (16B chunk)
  const u16* a0 = Abh + (long long)(m0 + srow) * lda + scol;
  const u16* a1 = Abl + (long long)(m0 + srow) * lda + scol;
  const u16* b0 = Bbh + (long long)(n0 + srow) * lda + scol;
  const u16* b1 = Bbl + (long long)(n0 + srow) * lda + scol;
  const long long half = (long long)64 * lda;

  const int lane = tid & 63, wid = tid >> 6;
  const int wr = wid >> 1, wc = wid & 1;
  const int fr = lane & 15, fq = lane >> 4;

  f32x4 acc[4][4] = {};

  { // prologue: stage step 0 into buffer 0
    char* d = lds + tid * 16;
    gl16(a0, d);          gl16(a0 + half, d + 4096);
    gl16(a1, d + 8192);   gl16(a1 + half, d + 12288);
    gl16(b0, d + 16384);  gl16(b0 + half, d + 20480);
    gl16(b1, d + 24576);  gl16(b1 + half, d + 28672);
  }

  const int NS = Kd / 32;
  for (int s = 0; s < NS; ++s) {
    const int bb = (s & 1) << 15;
    __syncthreads();    // buf[s&1] landed; all waves' prior ds_reads drained

    if (s + 1 < NS) {   // stage next step into the other buffer (flies under MFMA)
      const int ko = (s + 1) * 32;
      char* d = lds + (((s + 1) & 1) << 15) + tid * 16;
      gl16(a0 + ko, d);          gl16(a0 + ko + half, d + 4096);
      gl16(a1 + ko, d + 8192);   gl16(a1 + ko + half, d + 12288);
      gl16(b0 + ko, d + 16384);  gl16(b0 + ko + half, d + 20480);
      gl16(b1 + ko, d + 24576);  gl16(b1 + ko + half, d + 28672);
    }

    const char* Ahs = lds + bb;
    const char* Als = lds + bb + 8192;
    const char* Bhs = lds + bb + 16384;
    const char* Bls = lds + bb + 24576;
    bf16x8 fah[4], fal[4], fbh[4], fbl[4];
    #pragma unroll
    for (int im = 0; im < 4; ++im) {
      const int off = (wr * 64 + im * 16 + fr) * 64 + fq * 16;
      fah[im] = *(const bf16x8*)(Ahs + off);
      fal[im] = *(const bf16x8*)(Als + off);
    }
    #pragma unroll
    for (int jn = 0; jn < 4; ++jn) {
      const int off = (wc * 64 + jn * 16 + fr) * 64 + fq * 16;
      fbh[jn] = *(const bf16x8*)(Bhs + off);
      fbl[jn] = *(const bf16x8*)(Bls + off);
    }
    #pragma unroll
    for (int im = 0; im < 4; ++im)
      #pragma unroll
      for (int jn = 0; jn < 4; ++jn) {
        acc[im][jn] = __builtin_amdgcn_mfma_f32_16x16x32_bf16(fah[im], fbh[jn], acc[im][jn], 0, 0, 0);
        acc[im][jn] = __builtin_amdgcn_mfma_f32_16x16x32_bf16(fah[im], fbl[jn], acc[im][jn], 0, 0, 0);
        acc[im][jn] = __builtin_amdgcn_mfma_f32_16x16x32_bf16(fal[im], fbh[jn], acc[im][jn], 0, 0, 0);
      }
  }

  // epilogue: C/D layout col=lane&15, row=(lane>>4)*4+reg  [verified rounds 3-8]
  #pragma unroll
  for (int im = 0; im < 4; ++im) {
    #pragma unroll
    for (int jn = 0; jn < 4; ++jn) {
      const int mbase = m0 + wr * 64 + im * 16 + fq * 4;
      const int n     = n0 + wc * 64 + jn * 16 + fr;
      #pragma unroll
      for (int reg = 0; reg < 4; ++reg) {
        const int m = mbase + reg;
        const float v = acc[im][jn][reg];
        if (EPI == 0) {
          u16 h = bfb(v);
          Ch[(long long)z * sC + (long long)m * Nsz + n] = h;
          Cl[(long long)z * sC + (long long)m * Nsz + n] = bfb(v - fromb(h));
        } else if (EPI == 1) {
          float e = expf(fmaf(sscale, v, spu[z * TT + m] + spv[z * TT + n]));
          if (m == n) e = 0.f;
          Cf[(long long)z * sC + (long long)m * Nsz + n] = e;
        } else {
          Cf[(long long)z * sC + (long long)m * Nsz + n] = v;
        }
      }
    }
  }
}

// sum 4 split-K partials -> split bf16 hi/lo
__global__ void combine_ht(const float* __restrict__ part, u16* __restrict__ hi,
                           u16* __restrict__ lo) {
  const long long idx = (long long)blockIdx.x * 256 + threadIdx.x;  // float4 units
  const long long NQ = (long long)DD * DD / 4;
  const float4* p = (const float4*)part;
  float4 a = p[idx], b = p[idx + NQ], c = p[idx + 2 * NQ], d = p[idx + 3 * NQ];
  float vv[4] = {a.x + b.x + c.x + d.x, a.y + b.y + c.y + d.y,
                 a.z + b.z + c.z + d.z, a.w + b.w + c.w + d.w};
  ushort4 h, l;
  u16* hp = (u16*)&h; u16* lp = (u16*)&l;
  #pragma unroll
  for (int e = 0; e < 4; ++e) {
    u16 hh = bfb(vv[e]);
    hp[e] = hh; lp[e] = bfb(vv[e] - fromb(hh));
  }
  ((ushort4*)hi)[idx] = h;
  ((ushort4*)lo)[idx] = l;
}

// Fused colsum + Laplacian build: L[b,0,j]=f[b,j]; L[b,i,j]=-A+(i==j)*colsum
__global__ void csbl_kernel(const float* __restrict__ Aall, const float* __restrict__ f,
                            float* __restrict__ L) {
  const int b = blockIdx.x, j = threadIdx.x;
  const float* Ab = Aall + (long long)b * TT * TT;
  float* Lb = L + (long long)b * TT * TT;
  float s = 0.f;
  for (int i = 0; i < TT; ++i) s += Ab[i * TT + j];
  Lb[j] = f[b * TT + j];
  for (int i = 1; i < TT; ++i) {
    float v = -Ab[i * TT + j];
    if (i == j) v += s;
    Lb[i * TT + j] = v;
  }
}

// 32x32 Gauss-Jordan inverse in one wave's registers (verified round 4).
template<bool ZLAST>
__device__ __forceinline__ void gj32(float* d, int rl, int h) {
  #pragma unroll
  for (int s = 0; s < 32; ++s) {
    const int t = ZLAST ? ((s + 1) & 31) : s;
    const int tl = t & 15, th = t >> 4;
    float rowv[16];
    #pragma unroll
    for (int j = 0; j < 16; ++j) rowv[j] = __shfl(d[j], t + 32 * h);
    const float pv   = __shfl(d[tl], t + 32 * th);
    const float colv = __shfl(d[tl], rl + 32 * th);
    const float ip = 1.0f / pv;
    if (rl == t) {
      #pragma unroll
      for (int j = 0; j < 16; ++j) {
        float v = rowv[j] * ip;
        if (j == tl) v = (h == th) ? ip : v;
        d[j] = v;
      }
    } else {
      const float cip = colv * ip;
      #pragma unroll
      for (int j = 0; j < 16; ++j) {
        float v = fmaf(-cip, rowv[j], d[j]);
        if (j == tl) v = (h == th) ? -cip : v;
        d[j] = v;
      }
    }
  }
}

// Single-block-per-matrix blocked Gauss-Jordan, 512 threads (8 waves, 2/SIMD
// for TLP — round-8's 4-wave version was 98% latency-stalled). Same verified
// panel math as rounds 5-8. Changes vs round 8:
//  - split(-C) LDS staging DELETED: step 4 reads C directly from global at
//    step-4 time + in-register split. Safe: MFMA output row i depends only on
//    A-fragment row i; pivot-row lanes read post-step-3 values but their
//    outputs are discarded by the pivot-row skip; non-pivot rows' P-columns
//    are untouched until their own RMW (chunk-disjoint rows).
//  - step 3 spread over 8 waves (32 cols each, in-place, race-free);
//    step 4 = 2 chunks of 128 rows.
// LDS: RT split [256][40] x2 + Dinv split [32][40] x2 = 46080 B.
#define G1_RTH 0
#define G1_RTL 20480
#define G1_DH  40960
#define G1_DL  43520
#define G1_LDS 46080
__global__ __launch_bounds__(512, 2) void gj_single(float* __restrict__ Mg) {
  extern __shared__ char lds[];
  u16* RTh = (u16*)(lds + G1_RTH);
  u16* RTl = (u16*)(lds + G1_RTL);
  u16* Dh  = (u16*)(lds + G1_DH);
  u16* Dl  = (u16*)(lds + G1_DL);
  float* M = Mg + (long long)blockIdx.x * TT * TT;
  const int tid = threadIdx.x, wid = tid >> 6, lane = tid & 63;
  const int fr = lane & 15, fq = lane >> 4;

  for (int pi = 0; pi < 8; ++pi) {
    const int p = (pi + 1) & 7;
    const int P0 = p * NB;

    // ---- step 1: stage R^T split. 512 threads x 16 elems: row sr=tid&31,
    // cols cb..cb+15 with cb=(tid>>5)*16.
    {
      const int sr = tid & 31, cb = (tid >> 5) * 16;
      const float4* src = (const float4*)(M + (long long)(P0 + sr) * TT + cb);
      #pragma unroll
      for (int q = 0; q < 4; ++q) {
        float4 v = src[q];
        float vv[4] = {v.x, v.y, v.z, v.w};
        #pragma unroll
        for (int l = 0; l < 4; ++l) {
          const int j = cb + q * 4 + l;
          u16 h = bfb(vv[l]);
          RTh[j * 40 + sr] = h;
          RTl[j * 40 + sr] = bfb(vv[l] - fromb(h));
        }
      }
    }
    __syncthreads();

    // ---- step 2: wave 0 computes Dinv
    if (wid == 0) {
      const int rl = lane & 31, h2 = lane >> 5;
      float d[16];
      #pragma unroll
      for (int j = 0; j < 16; ++j) {
        const int col = P0 + h2 * 16 + j;
        d[j] = fromb(RTh[col * 40 + rl]) + fromb(RTl[col * 40 + rl]);
      }
      if (p == 0) gj32<true>(d, rl, h2); else gj32<false>(d, rl, h2);
      #pragma unroll
      for (int j = 0; j < 16; ++j) {
        u16 hh = bfb(d[j]);
        Dh[rl * 40 + h2 * 16 + j] = hh;
        Dl[rl * 40 + h2 * 16 + j] = bfb(d[j] - fromb(hh));
      }
    }
    __syncthreads();

    // ---- step 3: Rp = Dinv @ R, in-place into RT; write M pivot rows.
    // Each wave owns 32 columns (j = wid*32 + cf*16 + fr) -> race-free.
    #pragma unroll
    for (int cf = 0; cf < 2; ++cf) {
      const int j = wid * 32 + cf * 16 + fr;
      const bf16x8 bh = *(const bf16x8*)&RTh[j * 40 + fq * 8];
      const bf16x8 bl = *(const bf16x8*)&RTl[j * 40 + fq * 8];
      const bool inP = ((unsigned)(j - P0)) < 32u;
      const int s = j - P0;
      f32x4 acc2[2];
      #pragma unroll
      for (int fi = 0; fi < 2; ++fi) {
        const bf16x8 ah = *(const bf16x8*)&Dh[(fi * 16 + fr) * 40 + fq * 8];
        const bf16x8 al = *(const bf16x8*)&Dl[(fi * 16 + fr) * 40 + fq * 8];
        f32x4 a = {};
        a = __builtin_amdgcn_mfma_f32_16x16x32_bf16(ah, bh, a, 0, 0, 0);
        a = __builtin_amdgcn_mfma_f32_16x16x32_bf16(ah, bl, a, 0, 0, 0);
        a = __builtin_amdgcn_mfma_f32_16x16x32_bf16(al, bh, a, 0, 0, 0);
        acc2[fi] = a;
      }
      #pragma unroll
      for (int fi = 0; fi < 2; ++fi) {
        ushort4 oh, ol;
        u16* hp = (u16*)&oh; u16* lp = (u16*)&ol;
        float mvals[4];
        #pragma unroll
        for (int reg = 0; reg < 4; ++reg) {
          const int t = fi * 16 + fq * 4 + reg;
          float v = acc2[fi][reg];
          if (inP) v = fromb(Dh[t * 40 + s]) + fromb(Dl[t * 40 + s]);  // exact Dinv
          mvals[reg] = v;
          float rv = inP ? (v + ((t == s) ? 1.0f : 0.0f)) : v;  // staging: Dinv+I
          u16 hh = bfb(rv);
          hp[reg] = hh;
          lp[reg] = bfb(rv - fromb(hh));
        }
        *(ushort4*)&RTh[j * 40 + fi * 16 + fq * 4] = oh;
        *(ushort4*)&RTl[j * 40 + fi * 16 + fq * 4] = ol;
        #pragma unroll
        for (int reg = 0; reg < 4; ++reg)
          M[(long long)(P0 + fi * 16 + fq * 4 + reg) * TT + j] = mvals[reg];
      }
    }
    __syncthreads();   // RT holds RpB^T for ALL columns; update reads all

    // ---- step 4: rank-32 update, 2 chunks of 128 rows (wave: 16 rows/chunk).
    // A-operand = split(-C) read directly from global (pre-update P-columns).
    #pragma unroll 1
    for (int ch = 0; ch < 2; ++ch) {
      const int r0 = ch * 128 + wid * 16;
      bf16x8 ah, al;
      {
        const float4* cp = (const float4*)(M + (long long)(r0 + fr) * TT + P0 + fq * 8);
        float4 c0 = cp[0], c1 = cp[1];
        float cv[8] = {c0.x, c0.y, c0.z, c0.w, c1.x, c1.y, c1.z, c1.w};
        u16 hbuf[8], lbuf[8];
        #pragma unroll
        for (int e = 0; e < 8; ++e) {
          float x = -cv[e];
          u16 h = bfb(x);
          hbuf[e] = h; lbuf[e] = bfb(x - fromb(h));
        }
        ah = *(const bf16x8*)hbuf;
        al = *(const bf16x8*)lbuf;
      }
      f32x4 acc[16];
      #pragma unroll
      for (int cf = 0; cf < 16; ++cf) {
        const int j = cf * 16 + fr;
        const bf16x8 bh = *(const bf16x8*)&RTh[j * 40 + fq * 8];
        const bf16x8 bl = *(const bf16x8*)&RTl[j * 40 + fq * 8];
        f32x4 a = {};
        a = __builtin_amdgcn_mfma_f32_16x16x32_bf16(ah, bh, a, 0, 0, 0);
        a = __builtin_amdgcn_mfma_f32_16x16x32_bf16(ah, bl, a, 0, 0, 0);
        a = __builtin_amdgcn_mfma_f32_16x16x32_bf16(al, bh, a, 0, 0, 0);
        acc[cf] = a;
      }
      #pragma unroll
      for (int reg = 0; reg < 4; ++reg) {
        const int m = r0 + fq * 4 + reg;
        if ((unsigned)(m - P0) < 32u) continue;   // pivot rows done in step 3
        #pragma unroll
        for (int cf = 0; cf < 16; ++cf) {
          const int n = cf * 16 + fr;
          M[(long long)m * TT + n] += acc[cf][reg];
        }
      }
    }
    __syncthreads();   // M updated + staging free before next panel
  }
}

__global__ void out_kernel(const float* __restrict__ Aall, const float* __restrict__ Linv,
                           const float* __restrict__ f, float* __restrict__ out) {
  int bj = blockIdx.x;
  int b = bj >> 8, j = bj & 255;
  const float* Lrow = Linv + (long long)b * TT * TT + j * TT;
  const float* Ab   = Aall + (long long)b * TT * TT;
  float fbj = f[bj];
  float dg = Lrow[j];
  float l0 = Lrow[0];
  float* orow = out + (long long)bj * (TT + 1);
  for (int c = threadIdx.x; c < TT + 1; c += 256) {
    float v;
    if (c == 0) v = fbj * l0;
    else {
      int i = c - 1;
      float aij = Ab[i * TT + j];
      float t1 = (j > 0) ? dg : 0.f;
      float t2 = (i > 0) ? Lrow[i] : 0.f;
      v = aij * (t1 - t2);
    }
    orow[c] = v;
  }
}

extern "C" void kernel_launch(void* const* d_in, const int* in_sizes, int n_in,
                              void* d_out, int out_size, void* d_ws, size_t ws_size,
                              hipStream_t stream) {
  const float* inp = (const float*)d_in[0];
  const float* Wk  = (const float*)d_in[1];
  const float* bk  = (const float*)d_in[2];
  const float* Wq  = (const float*)d_in[3];
  const float* bq  = (const float*)d_in[4];
  const float* Wr  = (const float*)d_in[5];
  const float* br  = (const float*)d_in[6];
  float* out = (float*)d_out;

  // workspace layout (~117.5 MiB peak; 126 MiB proven available round 1)
  const long long NI = (long long)BB * TT * DD;   // 12,582,912
  u16* inpHi = (u16*)d_ws;
  u16* inpLo = inpHi + NI;
  u16* Zhi   = inpLo + NI;
  u16* Zlo   = Zhi + NI;
  u16* HTh   = Zlo + NI;
  u16* HTl   = HTh + (long long)DD * DD;
  u16* WqTh  = HTl + (long long)DD * DD;          // region later reused by A_
  u16* WqTl  = WqTh + (long long)DD * DD;
  u16* WkTh  = WqTl + (long long)DD * DD;
  u16* WkTl  = WkTh + (long long)DD * DD;
  float* A_  = (float*)WqTh;                      // aliases WqT/WkT (dead by einsum)
  float* f   = A_ + (long long)BB * TT * TT;
  float* cs  = f + BB * TT;                       // (unused slot kept for layout)
  float* us  = cs + BB * TT;
  float* vs_ = us + DD;
  float* spu = vs_ + DD;
  float* spv = spu + BB * TT;
  float* c0f = spv + BB * TT;
  // Z region reused: HT split-K partials (before Z), then L (after einsum)
  float* HTpart = (float*)Zhi;                    // 4 x DD x DD f32 = 16 MB
  float* L   = (float*)Zhi;

  (void)hipFuncSetAttribute(reinterpret_cast<const void*>(&pg_kernel<0>),
                            hipFuncAttributeMaxDynamicSharedMemorySize, 65536);
  (void)hipFuncSetAttribute(reinterpret_cast<const void*>(&pg_kernel<1>),
                            hipFuncAttributeMaxDynamicSharedMemorySize, 65536);
  (void)hipFuncSetAttribute(reinterpret_cast<const void*>(&pg_kernel<2>),
                            hipFuncAttributeMaxDynamicSharedMemorySize, 65536);
  (void)hipFuncSetAttribute(reinterpret_cast<const void*>(&gj_single),
                            hipFuncAttributeMaxDynamicSharedMemorySize, G1_LDS);

  const float s = 0.03125f;
  const int M = BB * TT;  // 12288

  // 1. pre-split inp
  split_kernel<<<(int)(NI / 4 / 256), 256, 0, stream>>>(inp, inpHi, inpLo, (int)NI);

  // 2. WqT/WkT = transpose+split
  tsplit_kernel<<<dim3(32, 32, 2), dim3(32, 8), 0, stream>>>(Wq, Wk, WqTh, WqTl, WkTh, WkTl);

  // 3. bias helpers: c0 = s*bq.bk ; us = s*WqT.bk ; vs = s*WkT.bq
  c0_kernel<<<1, 256, 0, stream>>>(bq, bk, c0f);
  rootv_split_kernel<<<DD / 4, 256, 0, stream>>>(WqTh, WqTl, bk, us, s);
  rootv_split_kernel<<<DD / 4, 256, 0, stream>>>(WkTh, WkTl, bq, vs_, s);

  // 4. HT[e,d] = sum_n Wk[n,e]*Wq[n,d] via split-K (4 partials) + combine
  pg_kernel<2><<<dim3(8, 8, 4), 256, 65536, stream>>>(
      WkTh, WkTl, WqTh, WqTl, nullptr, nullptr, HTpart, nullptr, nullptr,
      0.f, 256, DD, DD, 256, 256, (long long)DD * DD);
  combine_ht<<<DD * DD / 4 / 256, 256, 0, stream>>>(HTpart, HTh, HTl);

  // 5. Z = X @ H  (overwrites HTpart region — stream-ordered after combine)
  pg_kernel<0><<<dim3(M / 128, DD / 128, 1), 256, 65536, stream>>>(
      inpHi, inpLo, HTh, HTl, Zhi, Zlo, nullptr, nullptr, nullptr,
      0.f, DD, DD, DD, 0, 0, 0);

  // 6. fused row dots: f = X.Wr+br ; spu = X.us+c0 ; spv = X.vs
  rootv3_kernel<<<M / 4, 256, 0, stream>>>(inp, Wr, br, us, vs_, c0f, f, spu, spv);

  // 7. A[b,t,s] = (t==s)?0:exp(s*(z_t.x_s) + spu[b,t] + spv[b,s])
  pg_kernel<1><<<dim3(TT / 128, TT / 128, BB), 256, 65536, stream>>>(
      Zhi, Zlo, inpHi, inpLo, nullptr, nullptr, A_, spu, spv,
      s, DD, TT, DD, (long long)TT * DD, (long long)TT * DD, (long long)TT * TT);

  // 8. fused colsum + Laplacian build (L aliases Zhi; Z dead after einsum)
  csbl_kernel<<<BB, TT, 0, stream>>>(A_, f, L);

  // 9. single-kernel blocked Gauss-Jordan inverse (panels 1..7 then 0)
  gj_single<<<BB, 512, G1_LDS, stream>>>(L);

  out_kernel<<<BB * TT, TT, 0, stream>>>(A_, L, f, out);
}